// Round 6
// baseline (470.458 us; speedup 1.0000x reference)
//
#include <hip/hip_runtime.h>
#include <hip/hip_bf16.h>
#include <math.h>

// Problem constants
#define B_  8
#define L_  128
#define V_  32000
#define D_  64
#define R1_ 128
#define R2_ 320
#define UP_ 640
#define SPLITS_ 50   // k-splits for stage A (640 k each)

typedef short bf16x8 __attribute__((ext_vector_type(8)));
typedef float f32x4 __attribute__((ext_vector_type(4)));

#define GLDS16(gp, lp)                                                         \
    __builtin_amdgcn_global_load_lds(                                          \
        (const __attribute__((address_space(1))) void*)(gp),                   \
        (__attribute__((address_space(3))) void*)(lp), 16, 0, 0)

static __device__ inline unsigned short f2bf(float x) {
    __hip_bfloat16 h = __float2bfloat16(x);
    return *reinterpret_cast<unsigned short*>(&h);
}

// hi/lo bf16 split: v ~= hi + lo with rel err ~2^-17
static __device__ inline void split1(float v, unsigned short& h, unsigned short& l) {
    unsigned short hb = f2bf(v);
    float hf = __uint_as_float(((unsigned int)hb) << 16);
    h = hb;
    l = f2bf(v - hf);
}

// ---------------------------------------------------------------------------
// prep_all v3: Wup2 conversion DELETED (final reg-stages fp32 directly).
//   blocks [0,800):      W_emb fp32 -> k-blocked bf16 hi/lo
//   blocks [800,1184):   positional-encoding linears
__global__ __launch_bounds__(320) void prep_all(const float* __restrict__ Wemb,
                                                unsigned short* __restrict__ Whb,
                                                unsigned short* __restrict__ Wlb,
                                                const float* __restrict__ W1,
                                                const float* __restrict__ b1,
                                                float* __restrict__ o1,
                                                const float* __restrict__ W2,
                                                const float* __restrict__ b2,
                                                float* __restrict__ o2,
                                                const float* __restrict__ W3,
                                                const float* __restrict__ b3,
                                                float* __restrict__ o3) {
    __shared__ float P[640];
    int bx = blockIdx.x, t = threadIdx.x;
    if (bx < 800) {
        int u = bx * 320 + t;   // 0 .. 256000-1
        int kb = u >> 6, row = u & 63;
        const float* s = Wemb + (size_t)row * 32000 + kb * 8;
        unsigned short h8[8], l8[8];
#pragma unroll
        for (int j = 0; j < 8; ++j) split1(s[j], h8[j], l8[j]);
        *(ushort4*)&Whb[(size_t)u * 8]     = *(ushort4*)&h8[0];
        *(ushort4*)&Whb[(size_t)u * 8 + 4] = *(ushort4*)&h8[4];
        *(ushort4*)&Wlb[(size_t)u * 8]     = *(ushort4*)&l8[0];
        *(ushort4*)&Wlb[(size_t)u * 8 + 4] = *(ushort4*)&l8[4];
    } else {
        int id = bx - 800;
        int l = id & 127;
        int stage = id >> 7;
        const float* W = (stage == 0) ? W1 : (stage == 1) ? W2 : W3;
        const float* bias = (stage == 0) ? b1 : (stage == 1) ? b2 : b3;
        float* out = (stage == 0) ? o1 : (stage == 1) ? o2 : o3;
        int outF = (stage == 0) ? 64 : (stage == 1) ? 128 : 320;
        int dEnc = 2 * outF;
        for (int m = t; m < dEnc; m += 320) {
            int i = m >> 1;
            float ang = (float)l * powf(10000.0f, -2.0f * (float)i / (float)dEnc);
            P[m] = (m & 1) ? cosf(ang) : sinf(ang);
        }
        __syncthreads();
        if (t < outF) {
            float acc = bias[t];
            const float4* w = (const float4*)(W + (size_t)t * dEnc);
            for (int m4 = 0; m4 < dEnc / 4; ++m4) {
                float4 wv = w[m4];
                float4 pv = *(const float4*)&P[m4 * 4];
                acc = fmaf(pv.x, wv.x, acc);
                acc = fmaf(pv.y, wv.y, acc);
                acc = fmaf(pv.z, wv.z, acc);
                acc = fmaf(pv.w, wv.w, acc);
            }
            out[l * outF + t] = fmaxf(acc, 0.f);
        }
    }
}

// ---------------------------------------------------------------------------
// Stage A via MFMA (unchanged).
__global__ __launch_bounds__(256) void embA_mfma(const float* __restrict__ x,
                                                 const unsigned short* __restrict__ Whb,
                                                 const unsigned short* __restrict__ Wlb,
                                                 float* __restrict__ partA) {
    __shared__ short lds[16384];   // 2 x 16 KB
    int t = threadIdx.x;
    int lane = t & 63, w = t >> 6;
    int ln = lane & 15, lg = lane >> 4;
    int rb = blockIdx.x, ks = blockIdx.y;
    int row0 = rb * 64;
    const float* xrow = x + (size_t)(row0 + w * 16 + ln) * 32000;

    f32x4 acc[4];
#pragma unroll
    for (int nt = 0; nt < 4; ++nt) acc[nt] = (f32x4){0.f, 0.f, 0.f, 0.f};

    float4 xc[4], xn[4];
    {
        int kb0 = (ks * 640) >> 3;
#pragma unroll
        for (int s = 0; s < 4; ++s) {
            int ubase = s * 256 + w * 64;
            const unsigned short* arr = (s < 2) ? Whb : Wlb;
            int uu = (s < 2) ? ubase : (ubase - 512);
            const char* gp = (const char*)arr + ((size_t)kb0 * 64 + uu + lane) * 16;
            char* lp = (char*)lds + ((s < 2) ? 0 : 8192) + uu * 16;
            GLDS16(gp, lp);
        }
        const float* bp = xrow + ks * 640 + lg * 8;
        xc[0] = ((const float4*)bp)[0];
        xc[1] = ((const float4*)bp)[1];
        xc[2] = ((const float4*)(bp + 32))[0];
        xc[3] = ((const float4*)(bp + 32))[1];
    }

#pragma unroll 2
    for (int ch = 0; ch < 10; ++ch) {
        __syncthreads();   // drains chunk-ch GLDS16 + x loads
        if (ch < 9) {      // kick chunk ch+1 into the other buffer
            int kb0 = (ks * 640 + (ch + 1) * 64) >> 3;
            int p = (ch + 1) & 1;
#pragma unroll
            for (int s = 0; s < 4; ++s) {
                int ubase = s * 256 + w * 64;
                const unsigned short* arr = (s < 2) ? Whb : Wlb;
                int uu = (s < 2) ? ubase : (ubase - 512);
                const char* gp = (const char*)arr + ((size_t)kb0 * 64 + uu + lane) * 16;
                char* lp = (char*)lds + p * 16384 + ((s < 2) ? 0 : 8192) + uu * 16;
                GLDS16(gp, lp);
            }
            const float* bp = xrow + ks * 640 + (ch + 1) * 64 + lg * 8;
            xn[0] = ((const float4*)bp)[0];
            xn[1] = ((const float4*)bp)[1];
            xn[2] = ((const float4*)(bp + 32))[0];
            xn[3] = ((const float4*)(bp + 32))[1];
        }
        bf16x8 ah[2], al[2];
#pragma unroll
        for (int kstep = 0; kstep < 2; ++kstep) {
            float f[8] = {xc[2 * kstep].x, xc[2 * kstep].y, xc[2 * kstep].z, xc[2 * kstep].w,
                          xc[2 * kstep + 1].x, xc[2 * kstep + 1].y, xc[2 * kstep + 1].z,
                          xc[2 * kstep + 1].w};
            unsigned short h8[8], l8[8];
#pragma unroll
            for (int j = 0; j < 8; ++j) split1(f[j], h8[j], l8[j]);
            ah[kstep] = *(bf16x8*)h8;
            al[kstep] = *(bf16x8*)l8;
        }
        const char* buf = (const char*)lds + (ch & 1) * 16384;
#pragma unroll
        for (int kstep = 0; kstep < 2; ++kstep) {
            int g = kstep * 4 + lg;
#pragma unroll
            for (int nt = 0; nt < 4; ++nt) {
                int nrow = nt * 16 + ln;
                bf16x8 bh = *(const bf16x8*)(buf + (g * 64 + nrow) * 16);
                bf16x8 bl = *(const bf16x8*)(buf + 8192 + (g * 64 + nrow) * 16);
                acc[nt] = __builtin_amdgcn_mfma_f32_16x16x32_bf16(ah[kstep], bh, acc[nt], 0, 0, 0);
                acc[nt] = __builtin_amdgcn_mfma_f32_16x16x32_bf16(ah[kstep], bl, acc[nt], 0, 0, 0);
                acc[nt] = __builtin_amdgcn_mfma_f32_16x16x32_bf16(al[kstep], bh, acc[nt], 0, 0, 0);
            }
        }
#pragma unroll
        for (int i = 0; i < 4; ++i) xc[i] = xn[i];
    }
#pragma unroll
    for (int nt = 0; nt < 4; ++nt)
#pragma unroll
        for (int r = 0; r < 4; ++r)
            partA[((size_t)ks * 1024 + row0 + w * 16 + lg * 4 + r) * 64 + nt * 16 + ln] =
                acc[nt][r];
}

// ---------------------------------------------------------------------------
// reduceA v2 (unchanged).
__global__ __launch_bounds__(64) void reduceA_kernel(const float* __restrict__ partA,
                                                     const float* __restrict__ bemb,
                                                     const float* __restrict__ pe1,
                                                     float* __restrict__ h1,
                                                     float* __restrict__ s1) {
    int lane = threadIdx.x;
    int row = blockIdx.x * 4 + (lane >> 4);
    int d0 = (lane & 15) * 4;
    float4 v = *(const float4*)&bemb[d0];
#pragma unroll 10
    for (int s = 0; s < SPLITS_; ++s) {
        float4 p = *(const float4*)&partA[((size_t)s * 1024 + row) * 64 + d0];
        v.x += p.x; v.y += p.y; v.z += p.z; v.w += p.w;
    }
    float4 pe = *(const float4*)&pe1[(row & 127) * 64 + d0];
    v.x = fmaxf(v.x, 0.f) + pe.x;
    v.y = fmaxf(v.y, 0.f) + pe.y;
    v.z = fmaxf(v.z, 0.f) + pe.z;
    v.w = fmaxf(v.w, 0.f) + pe.w;
    *(float4*)&h1[row * 64 + d0] = v;
    float sum = v.x + v.y + v.z + v.w;
#pragma unroll
    for (int off = 8; off >= 1; off >>= 1) sum += __shfl_down(sum, off);
    if ((lane & 15) == 0) s1[row] = sum;
}

// ---------------------------------------------------------------------------
// wr1 v2 (unchanged).
__global__ __launch_bounds__(256) void wr1_kernel(const float* __restrict__ Wred,
                                                  const float* __restrict__ s1,
                                                  float* __restrict__ Wr1) {
    __shared__ float ss[1024];
    __shared__ float pl[2048];
    int t = threadIdx.x, bb = blockIdx.x;
    for (int i = t; i < 1024; i += 256) ss[i] = s1[i];
    __syncthreads();
    int r = bb >> 1, jh = bb & 1;
    int jj = t & 31, ks = t >> 5;
    int j = jh * 32 + jj;
    float acc[8];
#pragma unroll
    for (int b = 0; b < 8; ++b) acc[b] = 0.f;
    const float* w = Wred + (size_t)r * 8192 + j;
#pragma unroll
    for (int kk = 0; kk < 16; ++kk) {
        int k = ks * 16 + kk;
        float wv = w[k * 64];
#pragma unroll
        for (int b = 0; b < 8; ++b) acc[b] = fmaf(ss[b * 128 + k], wv, acc[b]);
    }
#pragma unroll
    for (int b = 0; b < 8; ++b) pl[t * 8 + b] = acc[b];
    __syncthreads();
    int jj2 = t >> 3, b2 = t & 7;
    float sum = 0.f;
#pragma unroll
    for (int k2 = 0; k2 < 8; ++k2) sum += pl[(k2 * 32 + jj2) * 8 + b2];
    Wr1[((size_t)b2 * 128 + r) * 64 + jh * 32 + jj2] = sum;
}

// ---------------------------------------------------------------------------
// h2 (unchanged).
__global__ __launch_bounds__(128) void h2_kernel(const float* __restrict__ h1,
                                                 const float* __restrict__ Wr1,
                                                 const float* __restrict__ bred,
                                                 const float* __restrict__ pe2,
                                                 float* __restrict__ h2,
                                                 float* __restrict__ s2) {
    __shared__ float hrow[64];
    __shared__ float red[2];
    int row = blockIdx.x;
    int b = row >> 7, i = row & 127;
    int r = threadIdx.x;
    if (r < 64) hrow[r] = h1[row * 64 + r];
    __syncthreads();
    float acc = bred[r];
    const float4* w = (const float4*)(Wr1 + ((size_t)b * 128 + r) * 64);
#pragma unroll
    for (int j4 = 0; j4 < 16; ++j4) {
        float4 wv = w[j4];
        float4 hv = *(const float4*)&hrow[j4 * 4];
        acc = fmaf(hv.x, wv.x, acc);
        acc = fmaf(hv.y, wv.y, acc);
        acc = fmaf(hv.z, wv.z, acc);
        acc = fmaf(hv.w, wv.w, acc);
    }
    float val = fmaxf(acc, 0.f) + pe2[i * 128 + r];
    h2[row * 128 + r] = val;
    float sum = val;
    for (int off = 32; off > 0; off >>= 1) sum += __shfl_down(sum, off);
    if ((r & 63) == 0) red[r >> 6] = sum;
    __syncthreads();
    if (r == 0) s2[row] = red[0] + red[1];
}

// ---------------------------------------------------------------------------
// wr2 v2 (unchanged).
__global__ __launch_bounds__(256) void wr2_kernel(const float* __restrict__ Wred2,
                                                  const float* __restrict__ s2,
                                                  float* __restrict__ Wr2) {
    __shared__ float ss[1024];
    __shared__ float pl[2048];
    int t = threadIdx.x, r = blockIdx.x;
    for (int i = t; i < 1024; i += 256) ss[i] = s2[i];
    __syncthreads();
    int j = t & 127, ks = t >> 7;
    float acc[8];
#pragma unroll
    for (int b = 0; b < 8; ++b) acc[b] = 0.f;
    const float* w = Wred2 + (size_t)r * 16384 + j;
#pragma unroll 16
    for (int kk = 0; kk < 64; ++kk) {
        int k = ks * 64 + kk;
        float wv = w[k * 128];
#pragma unroll
        for (int b = 0; b < 8; ++b) acc[b] = fmaf(ss[b * 128 + k], wv, acc[b]);
    }
#pragma unroll
    for (int b = 0; b < 8; ++b) pl[t * 8 + b] = acc[b];
    __syncthreads();
#pragma unroll
    for (int ii = 0; ii < 4; ++ii) {
        int idx = t * 4 + ii;
        int j2 = idx >> 3, b2 = idx & 7;
        float sum = pl[j2 * 8 + b2] + pl[(128 + j2) * 8 + b2];
        Wr2[((size_t)b2 * 320 + r) * 128 + j2] = sum;
    }
}

// ---------------------------------------------------------------------------
// h3+h4 fused (unchanged).
__global__ __launch_bounds__(256) void h3h4_kernel(const float* __restrict__ h2,
                                                   const float* __restrict__ Wr2,
                                                   const float* __restrict__ bred2,
                                                   const float* __restrict__ pe3,
                                                   const float* __restrict__ Wup1,
                                                   const float* __restrict__ bup1,
                                                   unsigned short* __restrict__ h4b) {
    __shared__ float h2r[512];    // 4 rows x 128
    __shared__ float hsT[1280];   // hsT[r*4+q] = h3[row0+q][r]
    int t = threadIdx.x;
    int row0 = blockIdx.x * 4;
    int b = row0 >> 7;
    h2r[t] = h2[(size_t)row0 * 128 + t];
    h2r[t + 256] = h2[(size_t)row0 * 128 + t + 256];
    __syncthreads();
    int i_ = row0 & 127;
    for (int r = t; r < 320; r += 256) {
        const float4* w = (const float4*)(Wr2 + ((size_t)b * 320 + r) * 128);
        float a0 = bred2[r], a1 = a0, a2 = a0, a3 = a0;
#pragma unroll
        for (int j4 = 0; j4 < 32; ++j4) {
            float4 wv = w[j4];
            float4 q0 = *(const float4*)&h2r[0 * 128 + j4 * 4];
            float4 q1 = *(const float4*)&h2r[1 * 128 + j4 * 4];
            float4 q2 = *(const float4*)&h2r[2 * 128 + j4 * 4];
            float4 q3 = *(const float4*)&h2r[3 * 128 + j4 * 4];
            a0 = fmaf(q0.x, wv.x, a0); a0 = fmaf(q0.y, wv.y, a0);
            a0 = fmaf(q0.z, wv.z, a0); a0 = fmaf(q0.w, wv.w, a0);
            a1 = fmaf(q1.x, wv.x, a1); a1 = fmaf(q1.y, wv.y, a1);
            a1 = fmaf(q1.z, wv.z, a1); a1 = fmaf(q1.w, wv.w, a1);
            a2 = fmaf(q2.x, wv.x, a2); a2 = fmaf(q2.y, wv.y, a2);
            a2 = fmaf(q2.z, wv.z, a2); a2 = fmaf(q2.w, wv.w, a2);
            a3 = fmaf(q3.x, wv.x, a3); a3 = fmaf(q3.y, wv.y, a3);
            a3 = fmaf(q3.z, wv.z, a3); a3 = fmaf(q3.w, wv.w, a3);
        }
        hsT[r * 4 + 0] = fmaxf(a0, 0.f) + pe3[(i_ + 0) * 320 + r];
        hsT[r * 4 + 1] = fmaxf(a1, 0.f) + pe3[(i_ + 1) * 320 + r];
        hsT[r * 4 + 2] = fmaxf(a2, 0.f) + pe3[(i_ + 2) * 320 + r];
        hsT[r * 4 + 3] = fmaxf(a3, 0.f) + pe3[(i_ + 3) * 320 + r];
    }
    __syncthreads();
    for (int u = t; u < 640; u += 256) {
        float acc[4] = {0.f, 0.f, 0.f, 0.f};
        const float4* w = (const float4*)(Wup1 + (size_t)u * 320);
#pragma unroll 2
        for (int j4 = 0; j4 < 80; ++j4) {
            float4 wv = w[j4];
#pragma unroll
            for (int e = 0; e < 4; ++e) {
                float wc = (e == 0) ? wv.x : (e == 1) ? wv.y : (e == 2) ? wv.z : wv.w;
                float4 hv = *(const float4*)&hsT[(j4 * 4 + e) * 4];
                acc[0] = fmaf(hv.x, wc, acc[0]);
                acc[1] = fmaf(hv.y, wc, acc[1]);
                acc[2] = fmaf(hv.z, wc, acc[2]);
                acc[3] = fmaf(hv.w, wc, acc[3]);
            }
        }
        float bias = bup1[u];
#pragma unroll
        for (int q = 0; q < 4; ++q)
            h4b[(size_t)(row0 + q) * 640 + u] = f2bf(fmaxf(acc[q] + bias, 0.f));
    }
}

// ---------------------------------------------------------------------------
// final MFMA v5: A reg-staged from Wup2 fp32 (load->f2bf->ds_write, T14 async
// split: loads issued before MFMA, write after), B via GLDS16 from h4b.
// LDS layout identical to v4 (conflict-free 128-B interleaved rows); 2 x 24 KB
// -> 3 blocks/CU. Same f2bf RNE as the old prep conversion -> bit-identical.
__global__ __launch_bounds__(512) void final_mfma_kernel(
    const unsigned short* __restrict__ h4b,
    const float* __restrict__ Wup2,
    const float* __restrict__ bup2,
    const float* __restrict__ Wfin,
    const float* __restrict__ bfin,
    float* __restrict__ out) {
    __shared__ short tile[2][12288];       // 2 x 24 KB buffers
    __shared__ float redbuf[2][2][128];    // [b_local][l_half][v]

    int t = threadIdx.x;
    int lane = t & 63;
    int w = t >> 6;                 // 0..7
    int wv = w >> 2;                // v-half 0..1
    int wq = w & 3;                 // n-quadrant: b_local = wq>>1, l_half = wq&1
    int bl_ = wq >> 1, lh = wq & 1;
    int ln = lane & 15, lg = lane >> 4;
    int b0 = blockIdx.x * 2;
    int v0 = blockIdx.y * 128;

    f32x4 acc[4][4];
#pragma unroll
    for (int mt = 0; mt < 4; ++mt)
#pragma unroll
        for (int nt = 0; nt < 4; ++nt) acc[mt][nt] = (f32x4){0.f, 0.f, 0.f, 0.f};

    // A reg-staging: thread t owns phys 16B unit t of the A region (8 KB).
    // Inverse swizzle on the SOURCE; LDS write is linear at t*16.
    int prA = t >> 3;                       // phys row 0..63
    int lA = (t & 7) ^ (prA & 7);           // logical unit
    const float* srcA =
        Wup2 + (size_t)(v0 + 2 * prA + (lA >> 2)) * 640 + (lA & 3) * 8;

    // B staging via GLDS16 (2 wave-contiguous units per thread)
    auto stageB = [&](int ch, int p) {
#pragma unroll
        for (int s = 0; s < 2; ++s) {
            int q = w * 128 + s * 64 + lane;         // unit 0..1023
            int pr = q >> 3;                          // phys row 0..127
            int l = (q & 7) ^ (pr & 7);
            int region = l >> 2, g = l & 3;
            const char* gp = (const char*)h4b +
                (((size_t)(b0 + region) * 128 + pr) * 640 +
                 (size_t)(ch * 32 + g * 8)) * 2;
            char* lp = (char*)&tile[p][0] + 8192 + w * 2048 + s * 1024;
            GLDS16(gp, lp);
        }
    };

    // prologue: chunk 0 into buffer 0
    {
        float4 a0 = ((const float4*)srcA)[0];
        float4 a1 = ((const float4*)srcA)[1];
        stageB(0, 0);
        unsigned short u8[8] = {f2bf(a0.x), f2bf(a0.y), f2bf(a0.z), f2bf(a0.w),
                                f2bf(a1.x), f2bf(a1.y), f2bf(a1.z), f2bf(a1.w)};
        *(ushort4*)(&tile[0][0] + t * 8)     = *(ushort4*)&u8[0];
        *(ushort4*)(&tile[0][0] + t * 8 + 4) = *(ushort4*)&u8[4];
    }

#pragma unroll 2
    for (int ch = 0; ch < 20; ++ch) {
        __syncthreads();   // drains chunk-ch GLDS16 (vm) + A ds_writes (lgkm)
        float4 aN0, aN1;
        if (ch < 19) {     // issue next-chunk A loads + B GLDS16 early
            const float* s = srcA + (ch + 1) * 32;
            aN0 = ((const float4*)s)[0];
            aN1 = ((const float4*)s)[1];
            stageB(ch + 1, (ch + 1) & 1);
        }
        const char* buf = (const char*)&tile[ch & 1][0];
        bf16x8 aF[4], bF[4];
#pragma unroll
        for (int mt = 0; mt < 4; ++mt) {
            int rA = wv * 64 + mt * 16 + ln;
            int pr = rA >> 1;
            int unit = (((rA & 1) << 2) | lg) ^ (pr & 7);
            aF[mt] = *(const bf16x8*)(buf + pr * 128 + unit * 16);
        }
#pragma unroll
        for (int nt = 0; nt < 4; ++nt) {
            int rB = lh * 64 + nt * 16 + ln;
            int unit = ((bl_ << 2) | lg) ^ (rB & 7);
            bF[nt] = *(const bf16x8*)(buf + 8192 + rB * 128 + unit * 16);
        }
#pragma unroll
        for (int mt = 0; mt < 4; ++mt)
#pragma unroll
            for (int nt = 0; nt < 4; ++nt)
                acc[mt][nt] = __builtin_amdgcn_mfma_f32_16x16x32_bf16(
                    aF[mt], bF[nt], acc[mt][nt], 0, 0, 0);
        if (ch < 19) {     // convert + write A for chunk ch+1 (after compute)
            int p = (ch + 1) & 1;
            unsigned short u8[8] = {f2bf(aN0.x), f2bf(aN0.y), f2bf(aN0.z), f2bf(aN0.w),
                                    f2bf(aN1.x), f2bf(aN1.y), f2bf(aN1.z), f2bf(aN1.w)};
            *(ushort4*)(&tile[p][0] + t * 8)     = *(ushort4*)&u8[0];
            *(ushort4*)(&tile[p][0] + t * 8 + 4) = *(ushort4*)&u8[4];
        }
    }

    // Epilogue: C/D layout col(l)=lane&15, row(v)=(lane>>4)*4+reg
    float bfin0 = bfin[0];
#pragma unroll
    for (int mt = 0; mt < 4; ++mt) {
        float bu[4];
#pragma unroll
        for (int r = 0; r < 4; ++r)
            bu[r] = bup2[v0 + wv * 64 + mt * 16 + lg * 4 + r];
        float part[4] = {0.f, 0.f, 0.f, 0.f};
#pragma unroll
        for (int nt = 0; nt < 4; ++nt) {
            float wf = Wfin[lh * 64 + nt * 16 + ln];
#pragma unroll
            for (int r = 0; r < 4; ++r)
                part[r] += wf * fmaxf(acc[mt][nt][r] + bu[r], 0.f);
        }
#pragma unroll
        for (int off = 8; off >= 1; off >>= 1)
#pragma unroll
            for (int r = 0; r < 4; ++r) part[r] += __shfl_xor(part[r], off, 64);
        if (ln == 0) {
#pragma unroll
            for (int r = 0; r < 4; ++r)
                redbuf[bl_][lh][wv * 64 + mt * 16 + lg * 4 + r] = part[r];
        }
    }
    __syncthreads();
    if (t < 256) {
        int bb = t >> 7, v = t & 127;
        float vsum = redbuf[bb][0][v] + redbuf[bb][1][v] + bfin0;
        out[(size_t)(b0 + bb) * 32000 + v0 + v] = fmaxf(vsum, 0.f);
    }
}

// ---------------------------------------------------------------------------
extern "C" void kernel_launch(void* const* d_in, const int* in_sizes, int n_in,
                              void* d_out, int out_size, void* d_ws, size_t ws_size,
                              hipStream_t stream) {
    const float* x      = (const float*)d_in[0];
    const float* W_emb  = (const float*)d_in[1];
    const float* b_emb  = (const float*)d_in[2];
    const float* W_pos1 = (const float*)d_in[3];
    const float* b_pos1 = (const float*)d_in[4];
    const float* W_red  = (const float*)d_in[5];
    const float* b_red  = (const float*)d_in[6];
    const float* W_pos2 = (const float*)d_in[7];
    const float* b_pos2 = (const float*)d_in[8];
    const float* W_red2 = (const float*)d_in[9];
    const float* b_red2 = (const float*)d_in[10];
    const float* W_pos3 = (const float*)d_in[11];
    const float* b_pos3 = (const float*)d_in[12];
    const float* W_up1  = (const float*)d_in[13];
    const float* b_up1  = (const float*)d_in[14];
    const float* W_up2  = (const float*)d_in[15];
    const float* b_up2  = (const float*)d_in[16];
    const float* W_fin  = (const float*)d_in[17];
    const float* b_fin  = (const float*)d_in[18];
    float* out = (float*)d_out;

    float* ws  = (float*)d_ws;
    float* pe1 = ws;                 // 8192
    float* pe2 = pe1 + 8192;         // 16384
    float* pe3 = pe2 + 16384;        // 40960
    float* h1  = pe3 + 40960;        // 65536
    float* s1  = h1 + 65536;         // 1024
    float* Wr1 = s1 + 1024;          // 65536
    float* h2  = Wr1 + 65536;        // 131072
    float* s2  = h2 + 131072;        // 1024
    float* Wr2 = s2 + 1024;          // 327680
    float* h3  = Wr2 + 327680;       // 327680 (layout spacer)
    unsigned short* h4b = (unsigned short*)(h3 + 327680);     // 655360 shorts
    float* after = (float*)h4b + 327680;
    unsigned short* Whb = (unsigned short*)after;             // 2,048,000 shorts
    unsigned short* Wlb = Whb + 2048000;                      // 2,048,000 shorts
    float* partA = (float*)(Wlb + 2048000);                   // 3,276,800 floats

    prep_all<<<dim3(1184), 320, 0, stream>>>(W_emb, Whb, Wlb,
                                             W_pos1, b_pos1, pe1, W_pos2, b_pos2,
                                             pe2, W_pos3, b_pos3, pe3);
    embA_mfma<<<dim3(16, SPLITS_), 256, 0, stream>>>(x, Whb, Wlb, partA);
    reduceA_kernel<<<dim3(256), 64, 0, stream>>>(partA, b_emb, pe1, h1, s1);
    wr1_kernel<<<dim3(256), 256, 0, stream>>>(W_red, s1, Wr1);
    h2_kernel<<<dim3(1024), 128, 0, stream>>>(h1, Wr1, b_red, pe2, h2, s2);
    wr2_kernel<<<dim3(320), 256, 0, stream>>>(W_red2, s2, Wr2);
    h3h4_kernel<<<dim3(256), 256, 0, stream>>>(h2, Wr2, b_red2, pe3, W_up1,
                                               b_up1, h4b);
    final_mfma_kernel<<<dim3(4, 250), 512, 0, stream>>>(h4b, W_up2, b_up2, W_fin,
                                                        b_fin, out);
}

// Round 7
// 456.369 us; speedup vs baseline: 1.0309x; 1.0309x over previous
//
#include <hip/hip_runtime.h>
#include <hip/hip_bf16.h>
#include <math.h>

// Problem constants
#define B_  8
#define L_  128
#define V_  32000
#define D_  64
#define R1_ 128
#define R2_ 320
#define UP_ 640
#define SPLITS_ 50   // k-splits for stage A (640 k each)

typedef short bf16x8 __attribute__((ext_vector_type(8)));
typedef float f32x4 __attribute__((ext_vector_type(4)));

#define GLDS16(gp, lp)                                                         \
    __builtin_amdgcn_global_load_lds(                                          \
        (const __attribute__((address_space(1))) void*)(gp),                   \
        (__attribute__((address_space(3))) void*)(lp), 16, 0, 0)

static __device__ inline unsigned short f2bf(float x) {
    __hip_bfloat16 h = __float2bfloat16(x);
    return *reinterpret_cast<unsigned short*>(&h);
}

// hi/lo bf16 split: v ~= hi + lo with rel err ~2^-17
static __device__ inline void split1(float v, unsigned short& h, unsigned short& l) {
    unsigned short hb = f2bf(v);
    float hf = __uint_as_float(((unsigned int)hb) << 16);
    h = hb;
    l = f2bf(v - hf);
}

// ---------------------------------------------------------------------------
// prep_all (round-5 version: Wup2b conversion restored).
//   blocks [0,800):      W_emb fp32 -> k-blocked bf16 hi/lo
//   blocks [800,1184):   positional-encoding linears
//   blocks [1184,4384):  Wup2 fp32 -> bf16
__global__ __launch_bounds__(320) void prep_all(const float* __restrict__ Wemb,
                                                unsigned short* __restrict__ Whb,
                                                unsigned short* __restrict__ Wlb,
                                                const float* __restrict__ Wup2,
                                                unsigned short* __restrict__ Wup2b,
                                                const float* __restrict__ W1,
                                                const float* __restrict__ b1,
                                                float* __restrict__ o1,
                                                const float* __restrict__ W2,
                                                const float* __restrict__ b2,
                                                float* __restrict__ o2,
                                                const float* __restrict__ W3,
                                                const float* __restrict__ b3,
                                                float* __restrict__ o3) {
    __shared__ float P[640];
    int bx = blockIdx.x, t = threadIdx.x;
    if (bx < 800) {
        int u = bx * 320 + t;   // 0 .. 256000-1
        int kb = u >> 6, row = u & 63;
        const float* s = Wemb + (size_t)row * 32000 + kb * 8;
        unsigned short h8[8], l8[8];
#pragma unroll
        for (int j = 0; j < 8; ++j) split1(s[j], h8[j], l8[j]);
        *(ushort4*)&Whb[(size_t)u * 8]     = *(ushort4*)&h8[0];
        *(ushort4*)&Whb[(size_t)u * 8 + 4] = *(ushort4*)&h8[4];
        *(ushort4*)&Wlb[(size_t)u * 8]     = *(ushort4*)&l8[0];
        *(ushort4*)&Wlb[(size_t)u * 8 + 4] = *(ushort4*)&l8[4];
    } else if (bx < 1184) {
        int id = bx - 800;
        int l = id & 127;
        int stage = id >> 7;
        const float* W = (stage == 0) ? W1 : (stage == 1) ? W2 : W3;
        const float* bias = (stage == 0) ? b1 : (stage == 1) ? b2 : b3;
        float* out = (stage == 0) ? o1 : (stage == 1) ? o2 : o3;
        int outF = (stage == 0) ? 64 : (stage == 1) ? 128 : 320;
        int dEnc = 2 * outF;
        for (int m = t; m < dEnc; m += 320) {
            int i = m >> 1;
            float ang = (float)l * powf(10000.0f, -2.0f * (float)i / (float)dEnc);
            P[m] = (m & 1) ? cosf(ang) : sinf(ang);
        }
        __syncthreads();
        if (t < outF) {
            float acc = bias[t];
            const float4* w = (const float4*)(W + (size_t)t * dEnc);
            for (int m4 = 0; m4 < dEnc / 4; ++m4) {
                float4 wv = w[m4];
                float4 pv = *(const float4*)&P[m4 * 4];
                acc = fmaf(pv.x, wv.x, acc);
                acc = fmaf(pv.y, wv.y, acc);
                acc = fmaf(pv.z, wv.z, acc);
                acc = fmaf(pv.w, wv.w, acc);
            }
            out[l * outF + t] = fmaxf(acc, 0.f);
        }
    } else {
        const int n4 = (V_ * UP_) / 4;
        int stride = 3200 * 320;
        for (int i = (bx - 1184) * 320 + t; i < n4; i += stride) {
            float4 v = ((const float4*)Wup2)[i];
            ushort4 o;
            o.x = f2bf(v.x); o.y = f2bf(v.y); o.z = f2bf(v.z); o.w = f2bf(v.w);
            ((ushort4*)Wup2b)[i] = o;
        }
    }
}

// ---------------------------------------------------------------------------
// Stage A via MFMA (unchanged).
__global__ __launch_bounds__(256) void embA_mfma(const float* __restrict__ x,
                                                 const unsigned short* __restrict__ Whb,
                                                 const unsigned short* __restrict__ Wlb,
                                                 float* __restrict__ partA) {
    __shared__ short lds[16384];   // 2 x 16 KB
    int t = threadIdx.x;
    int lane = t & 63, w = t >> 6;
    int ln = lane & 15, lg = lane >> 4;
    int rb = blockIdx.x, ks = blockIdx.y;
    int row0 = rb * 64;
    const float* xrow = x + (size_t)(row0 + w * 16 + ln) * 32000;

    f32x4 acc[4];
#pragma unroll
    for (int nt = 0; nt < 4; ++nt) acc[nt] = (f32x4){0.f, 0.f, 0.f, 0.f};

    float4 xc[4], xn[4];
    {
        int kb0 = (ks * 640) >> 3;
#pragma unroll
        for (int s = 0; s < 4; ++s) {
            int ubase = s * 256 + w * 64;
            const unsigned short* arr = (s < 2) ? Whb : Wlb;
            int uu = (s < 2) ? ubase : (ubase - 512);
            const char* gp = (const char*)arr + ((size_t)kb0 * 64 + uu + lane) * 16;
            char* lp = (char*)lds + ((s < 2) ? 0 : 8192) + uu * 16;
            GLDS16(gp, lp);
        }
        const float* bp = xrow + ks * 640 + lg * 8;
        xc[0] = ((const float4*)bp)[0];
        xc[1] = ((const float4*)bp)[1];
        xc[2] = ((const float4*)(bp + 32))[0];
        xc[3] = ((const float4*)(bp + 32))[1];
    }

#pragma unroll 2
    for (int ch = 0; ch < 10; ++ch) {
        __syncthreads();   // drains chunk-ch GLDS16 + x loads
        if (ch < 9) {      // kick chunk ch+1 into the other buffer
            int kb0 = (ks * 640 + (ch + 1) * 64) >> 3;
            int p = (ch + 1) & 1;
#pragma unroll
            for (int s = 0; s < 4; ++s) {
                int ubase = s * 256 + w * 64;
                const unsigned short* arr = (s < 2) ? Whb : Wlb;
                int uu = (s < 2) ? ubase : (ubase - 512);
                const char* gp = (const char*)arr + ((size_t)kb0 * 64 + uu + lane) * 16;
                char* lp = (char*)lds + p * 16384 + ((s < 2) ? 0 : 8192) + uu * 16;
                GLDS16(gp, lp);
            }
            const float* bp = xrow + ks * 640 + (ch + 1) * 64 + lg * 8;
            xn[0] = ((const float4*)bp)[0];
            xn[1] = ((const float4*)bp)[1];
            xn[2] = ((const float4*)(bp + 32))[0];
            xn[3] = ((const float4*)(bp + 32))[1];
        }
        bf16x8 ah[2], al[2];
#pragma unroll
        for (int kstep = 0; kstep < 2; ++kstep) {
            float f[8] = {xc[2 * kstep].x, xc[2 * kstep].y, xc[2 * kstep].z, xc[2 * kstep].w,
                          xc[2 * kstep + 1].x, xc[2 * kstep + 1].y, xc[2 * kstep + 1].z,
                          xc[2 * kstep + 1].w};
            unsigned short h8[8], l8[8];
#pragma unroll
            for (int j = 0; j < 8; ++j) split1(f[j], h8[j], l8[j]);
            ah[kstep] = *(bf16x8*)h8;
            al[kstep] = *(bf16x8*)l8;
        }
        const char* buf = (const char*)lds + (ch & 1) * 16384;
#pragma unroll
        for (int kstep = 0; kstep < 2; ++kstep) {
            int g = kstep * 4 + lg;
#pragma unroll
            for (int nt = 0; nt < 4; ++nt) {
                int nrow = nt * 16 + ln;
                bf16x8 bh = *(const bf16x8*)(buf + (g * 64 + nrow) * 16);
                bf16x8 bl = *(const bf16x8*)(buf + 8192 + (g * 64 + nrow) * 16);
                acc[nt] = __builtin_amdgcn_mfma_f32_16x16x32_bf16(ah[kstep], bh, acc[nt], 0, 0, 0);
                acc[nt] = __builtin_amdgcn_mfma_f32_16x16x32_bf16(ah[kstep], bl, acc[nt], 0, 0, 0);
                acc[nt] = __builtin_amdgcn_mfma_f32_16x16x32_bf16(al[kstep], bh, acc[nt], 0, 0, 0);
            }
        }
#pragma unroll
        for (int i = 0; i < 4; ++i) xc[i] = xn[i];
    }
#pragma unroll
    for (int nt = 0; nt < 4; ++nt)
#pragma unroll
        for (int r = 0; r < 4; ++r)
            partA[((size_t)ks * 1024 + row0 + w * 16 + lg * 4 + r) * 64 + nt * 16 + ln] =
                acc[nt][r];
}

// ---------------------------------------------------------------------------
// reduceA v2 (unchanged).
__global__ __launch_bounds__(64) void reduceA_kernel(const float* __restrict__ partA,
                                                     const float* __restrict__ bemb,
                                                     const float* __restrict__ pe1,
                                                     float* __restrict__ h1,
                                                     float* __restrict__ s1) {
    int lane = threadIdx.x;
    int row = blockIdx.x * 4 + (lane >> 4);
    int d0 = (lane & 15) * 4;
    float4 v = *(const float4*)&bemb[d0];
#pragma unroll 10
    for (int s = 0; s < SPLITS_; ++s) {
        float4 p = *(const float4*)&partA[((size_t)s * 1024 + row) * 64 + d0];
        v.x += p.x; v.y += p.y; v.z += p.z; v.w += p.w;
    }
    float4 pe = *(const float4*)&pe1[(row & 127) * 64 + d0];
    v.x = fmaxf(v.x, 0.f) + pe.x;
    v.y = fmaxf(v.y, 0.f) + pe.y;
    v.z = fmaxf(v.z, 0.f) + pe.z;
    v.w = fmaxf(v.w, 0.f) + pe.w;
    *(float4*)&h1[row * 64 + d0] = v;
    float sum = v.x + v.y + v.z + v.w;
#pragma unroll
    for (int off = 8; off >= 1; off >>= 1) sum += __shfl_down(sum, off);
    if ((lane & 15) == 0) s1[row] = sum;
}

// ---------------------------------------------------------------------------
// wr1 v2 (unchanged).
__global__ __launch_bounds__(256) void wr1_kernel(const float* __restrict__ Wred,
                                                  const float* __restrict__ s1,
                                                  float* __restrict__ Wr1) {
    __shared__ float ss[1024];
    __shared__ float pl[2048];
    int t = threadIdx.x, bb = blockIdx.x;
    for (int i = t; i < 1024; i += 256) ss[i] = s1[i];
    __syncthreads();
    int r = bb >> 1, jh = bb & 1;
    int jj = t & 31, ks = t >> 5;
    int j = jh * 32 + jj;
    float acc[8];
#pragma unroll
    for (int b = 0; b < 8; ++b) acc[b] = 0.f;
    const float* w = Wred + (size_t)r * 8192 + j;
#pragma unroll
    for (int kk = 0; kk < 16; ++kk) {
        int k = ks * 16 + kk;
        float wv = w[k * 64];
#pragma unroll
        for (int b = 0; b < 8; ++b) acc[b] = fmaf(ss[b * 128 + k], wv, acc[b]);
    }
#pragma unroll
    for (int b = 0; b < 8; ++b) pl[t * 8 + b] = acc[b];
    __syncthreads();
    int jj2 = t >> 3, b2 = t & 7;
    float sum = 0.f;
#pragma unroll
    for (int k2 = 0; k2 < 8; ++k2) sum += pl[(k2 * 32 + jj2) * 8 + b2];
    Wr1[((size_t)b2 * 128 + r) * 64 + jh * 32 + jj2] = sum;
}

// ---------------------------------------------------------------------------
// h2 (unchanged).
__global__ __launch_bounds__(128) void h2_kernel(const float* __restrict__ h1,
                                                 const float* __restrict__ Wr1,
                                                 const float* __restrict__ bred,
                                                 const float* __restrict__ pe2,
                                                 float* __restrict__ h2,
                                                 float* __restrict__ s2) {
    __shared__ float hrow[64];
    __shared__ float red[2];
    int row = blockIdx.x;
    int b = row >> 7, i = row & 127;
    int r = threadIdx.x;
    if (r < 64) hrow[r] = h1[row * 64 + r];
    __syncthreads();
    float acc = bred[r];
    const float4* w = (const float4*)(Wr1 + ((size_t)b * 128 + r) * 64);
#pragma unroll
    for (int j4 = 0; j4 < 16; ++j4) {
        float4 wv = w[j4];
        float4 hv = *(const float4*)&hrow[j4 * 4];
        acc = fmaf(hv.x, wv.x, acc);
        acc = fmaf(hv.y, wv.y, acc);
        acc = fmaf(hv.z, wv.z, acc);
        acc = fmaf(hv.w, wv.w, acc);
    }
    float val = fmaxf(acc, 0.f) + pe2[i * 128 + r];
    h2[row * 128 + r] = val;
    float sum = val;
    for (int off = 32; off > 0; off >>= 1) sum += __shfl_down(sum, off);
    if ((r & 63) == 0) red[r >> 6] = sum;
    __syncthreads();
    if (r == 0) s2[row] = red[0] + red[1];
}

// ---------------------------------------------------------------------------
// wr2 v2 (unchanged).
__global__ __launch_bounds__(256) void wr2_kernel(const float* __restrict__ Wred2,
                                                  const float* __restrict__ s2,
                                                  float* __restrict__ Wr2) {
    __shared__ float ss[1024];
    __shared__ float pl[2048];
    int t = threadIdx.x, r = blockIdx.x;
    for (int i = t; i < 1024; i += 256) ss[i] = s2[i];
    __syncthreads();
    int j = t & 127, ks = t >> 7;
    float acc[8];
#pragma unroll
    for (int b = 0; b < 8; ++b) acc[b] = 0.f;
    const float* w = Wred2 + (size_t)r * 16384 + j;
#pragma unroll 16
    for (int kk = 0; kk < 64; ++kk) {
        int k = ks * 64 + kk;
        float wv = w[k * 128];
#pragma unroll
        for (int b = 0; b < 8; ++b) acc[b] = fmaf(ss[b * 128 + k], wv, acc[b]);
    }
#pragma unroll
    for (int b = 0; b < 8; ++b) pl[t * 8 + b] = acc[b];
    __syncthreads();
#pragma unroll
    for (int ii = 0; ii < 4; ++ii) {
        int idx = t * 4 + ii;
        int j2 = idx >> 3, b2 = idx & 7;
        float sum = pl[j2 * 8 + b2] + pl[(128 + j2) * 8 + b2];
        Wr2[((size_t)b2 * 320 + r) * 128 + j2] = sum;
    }
}

// ---------------------------------------------------------------------------
// h3+h4 fused (unchanged).
__global__ __launch_bounds__(256) void h3h4_kernel(const float* __restrict__ h2,
                                                   const float* __restrict__ Wr2,
                                                   const float* __restrict__ bred2,
                                                   const float* __restrict__ pe3,
                                                   const float* __restrict__ Wup1,
                                                   const float* __restrict__ bup1,
                                                   unsigned short* __restrict__ h4b) {
    __shared__ float h2r[512];    // 4 rows x 128
    __shared__ float hsT[1280];   // hsT[r*4+q] = h3[row0+q][r]
    int t = threadIdx.x;
    int row0 = blockIdx.x * 4;
    int b = row0 >> 7;
    h2r[t] = h2[(size_t)row0 * 128 + t];
    h2r[t + 256] = h2[(size_t)row0 * 128 + t + 256];
    __syncthreads();
    int i_ = row0 & 127;
    for (int r = t; r < 320; r += 256) {
        const float4* w = (const float4*)(Wr2 + ((size_t)b * 320 + r) * 128);
        float a0 = bred2[r], a1 = a0, a2 = a0, a3 = a0;
#pragma unroll
        for (int j4 = 0; j4 < 32; ++j4) {
            float4 wv = w[j4];
            float4 q0 = *(const float4*)&h2r[0 * 128 + j4 * 4];
            float4 q1 = *(const float4*)&h2r[1 * 128 + j4 * 4];
            float4 q2 = *(const float4*)&h2r[2 * 128 + j4 * 4];
            float4 q3 = *(const float4*)&h2r[3 * 128 + j4 * 4];
            a0 = fmaf(q0.x, wv.x, a0); a0 = fmaf(q0.y, wv.y, a0);
            a0 = fmaf(q0.z, wv.z, a0); a0 = fmaf(q0.w, wv.w, a0);
            a1 = fmaf(q1.x, wv.x, a1); a1 = fmaf(q1.y, wv.y, a1);
            a1 = fmaf(q1.z, wv.z, a1); a1 = fmaf(q1.w, wv.w, a1);
            a2 = fmaf(q2.x, wv.x, a2); a2 = fmaf(q2.y, wv.y, a2);
            a2 = fmaf(q2.z, wv.z, a2); a2 = fmaf(q2.w, wv.w, a2);
            a3 = fmaf(q3.x, wv.x, a3); a3 = fmaf(q3.y, wv.y, a3);
            a3 = fmaf(q3.z, wv.z, a3); a3 = fmaf(q3.w, wv.w, a3);
        }
        hsT[r * 4 + 0] = fmaxf(a0, 0.f) + pe3[(i_ + 0) * 320 + r];
        hsT[r * 4 + 1] = fmaxf(a1, 0.f) + pe3[(i_ + 1) * 320 + r];
        hsT[r * 4 + 2] = fmaxf(a2, 0.f) + pe3[(i_ + 2) * 320 + r];
        hsT[r * 4 + 3] = fmaxf(a3, 0.f) + pe3[(i_ + 3) * 320 + r];
    }
    __syncthreads();
    for (int u = t; u < 640; u += 256) {
        float acc[4] = {0.f, 0.f, 0.f, 0.f};
        const float4* w = (const float4*)(Wup1 + (size_t)u * 320);
#pragma unroll 2
        for (int j4 = 0; j4 < 80; ++j4) {
            float4 wv = w[j4];
#pragma unroll
            for (int e = 0; e < 4; ++e) {
                float wc = (e == 0) ? wv.x : (e == 1) ? wv.y : (e == 2) ? wv.z : wv.w;
                float4 hv = *(const float4*)&hsT[(j4 * 4 + e) * 4];
                acc[0] = fmaf(hv.x, wc, acc[0]);
                acc[1] = fmaf(hv.y, wc, acc[1]);
                acc[2] = fmaf(hv.z, wc, acc[2]);
                acc[3] = fmaf(hv.w, wc, acc[3]);
            }
        }
        float bias = bup1[u];
#pragma unroll
        for (int q = 0; q < 4; ++q)
            h4b[(size_t)(row0 + q) * 640 + u] = f2bf(fmaxf(acc[q] + bias, 0.f));
    }
}

// ---------------------------------------------------------------------------
// final MFMA v6: tail-effect fix. Block 256 thr (4 waves), tile 128v x 128l x
// 1 batch, grid (8 b, 250 v) = 2000 blocks. LDS: 2 x 16 KB dbuf + 1 KB redbuf
// = 33 KB -> 4 blocks/CU (__launch_bounds__(256,4)) -> 1024 resident, 98%
// envelope vs 65% before. A and B both use the PROVEN conflict-free layout
// (2 logical rows per 128-B phys row; unit = (4o+lg)^(pr&7); 0 conflicts in
// r5/r6 counters). Same chunk order & MFMA sequence => bit-identical output.
__global__ __launch_bounds__(256, 4) void final_mfma_kernel(
    const unsigned short* __restrict__ h4b,
    const unsigned short* __restrict__ Wup2b,
    const float* __restrict__ bup2,
    const float* __restrict__ Wfin,
    const float* __restrict__ bfin,
    float* __restrict__ out) {
    __shared__ short tile[2][8192];        // 2 x 16 KB buffers
    __shared__ float redbuf[2][128];       // [l_half][v]

    int t = threadIdx.x;
    int lane = t & 63;
    int w = t >> 6;                 // 0..3
    int wv = w >> 1;                // v-half 0..1
    int lh = w & 1;                 // l-half 0..1
    int ln = lane & 15, lg = lane >> 4;
    int b = blockIdx.x;             // batch 0..7
    int v0 = blockIdx.y * 128;

    f32x4 acc[4][4];
#pragma unroll
    for (int mt = 0; mt < 4; ++mt)
#pragma unroll
        for (int nt = 0; nt < 4; ++nt) acc[mt][nt] = (f32x4){0.f, 0.f, 0.f, 0.f};

    // stage chunk ch (32 k) into buffer p: 1024 16B-units, 4 per thread.
    // A units 0..511 (64 phys rows x 8), B units 512..1023.
    // Source carries the inverse of the read-side unit swizzle.
    auto stage = [&](int ch, int p) {
#pragma unroll
        for (int s = 0; s < 4; ++s) {
            int seg = w * 4 + s;                     // 0..15
            int q = seg * 64 + lane;                 // unit 0..1023
            const char* gp;
            if (q < 512) {                           // A: Wup2b
                int pr = q >> 3, u = q & 7;
                int l = u ^ (pr & 7);
                int o = l >> 2, g = l & 3;
                gp = (const char*)Wup2b +
                     (((size_t)(v0 + 2 * pr + o)) * 640 +
                      (size_t)(ch * 32 + g * 8)) * 2;
            } else {                                 // B: h4b
                int q2 = q - 512;
                int pr = q2 >> 3, u = q2 & 7;
                int l = u ^ (pr & 7);
                int o = l >> 2, g = l & 3;
                gp = (const char*)h4b +
                     (((size_t)b * 128 + 2 * pr + o) * 640 +
                      (size_t)(ch * 32 + g * 8)) * 2;
            }
            char* lp = (char*)&tile[p][0] + seg * 1024;   // wave-uniform
            GLDS16(gp, lp);
        }
    };

    stage(0, 0);

#pragma unroll 2
    for (int ch = 0; ch < 20; ++ch) {
        __syncthreads();                  // drains chunk-ch GLDS16
        if (ch < 19) stage(ch + 1, (ch + 1) & 1);
        const char* buf = (const char*)&tile[ch & 1][0];
        bf16x8 aF[4], bF[4];
#pragma unroll
        for (int mt = 0; mt < 4; ++mt) {
            int rA = wv * 64 + mt * 16 + ln;
            int pr = rA >> 1;
            int unit = (((rA & 1) << 2) | lg) ^ (pr & 7);
            aF[mt] = *(const bf16x8*)(buf + pr * 128 + unit * 16);
        }
#pragma unroll
        for (int nt = 0; nt < 4; ++nt) {
            int rB = lh * 64 + nt * 16 + ln;
            int pr = rB >> 1;
            int unit = (((rB & 1) << 2) | lg) ^ (pr & 7);
            bF[nt] = *(const bf16x8*)(buf + 8192 + pr * 128 + unit * 16);
        }
#pragma unroll
        for (int mt = 0; mt < 4; ++mt)
#pragma unroll
            for (int nt = 0; nt < 4; ++nt)
                acc[mt][nt] = __builtin_amdgcn_mfma_f32_16x16x32_bf16(
                    aF[mt], bF[nt], acc[mt][nt], 0, 0, 0);
    }

    // Epilogue: C/D layout col(l)=lane&15, row(v)=(lane>>4)*4+reg
    float bfin0 = bfin[0];
#pragma unroll
    for (int mt = 0; mt < 4; ++mt) {
        float bu[4];
#pragma unroll
        for (int r = 0; r < 4; ++r)
            bu[r] = bup2[v0 + wv * 64 + mt * 16 + lg * 4 + r];
        float part[4] = {0.f, 0.f, 0.f, 0.f};
#pragma unroll
        for (int nt = 0; nt < 4; ++nt) {
            float wf = Wfin[lh * 64 + nt * 16 + ln];
#pragma unroll
            for (int r = 0; r < 4; ++r)
                part[r] += wf * fmaxf(acc[mt][nt][r] + bu[r], 0.f);
        }
#pragma unroll
        for (int off = 8; off >= 1; off >>= 1)
#pragma unroll
            for (int r = 0; r < 4; ++r) part[r] += __shfl_xor(part[r], off, 64);
        if (ln == 0) {
#pragma unroll
            for (int r = 0; r < 4; ++r)
                redbuf[lh][wv * 64 + mt * 16 + lg * 4 + r] = part[r];
        }
    }
    __syncthreads();
    if (t < 128) {
        float vsum = redbuf[0][t] + redbuf[1][t] + bfin0;
        out[(size_t)b * 32000 + v0 + t] = fmaxf(vsum, 0.f);
    }
}

// ---------------------------------------------------------------------------
extern "C" void kernel_launch(void* const* d_in, const int* in_sizes, int n_in,
                              void* d_out, int out_size, void* d_ws, size_t ws_size,
                              hipStream_t stream) {
    const float* x      = (const float*)d_in[0];
    const float* W_emb  = (const float*)d_in[1];
    const float* b_emb  = (const float*)d_in[2];
    const float* W_pos1 = (const float*)d_in[3];
    const float* b_pos1 = (const float*)d_in[4];
    const float* W_red  = (const float*)d_in[5];
    const float* b_red  = (const float*)d_in[6];
    const float* W_pos2 = (const float*)d_in[7];
    const float* b_pos2 = (const float*)d_in[8];
    const float* W_red2 = (const float*)d_in[9];
    const float* b_red2 = (const float*)d_in[10];
    const float* W_pos3 = (const float*)d_in[11];
    const float* b_pos3 = (const float*)d_in[12];
    const float* W_up1  = (const float*)d_in[13];
    const float* b_up1  = (const float*)d_in[14];
    const float* W_up2  = (const float*)d_in[15];
    const float* b_up2  = (const float*)d_in[16];
    const float* W_fin  = (const float*)d_in[17];
    const float* b_fin  = (const float*)d_in[18];
    float* out = (float*)d_out;

    float* ws  = (float*)d_ws;
    float* pe1 = ws;                 // 8192
    float* pe2 = pe1 + 8192;         // 16384
    float* pe3 = pe2 + 16384;        // 40960
    float* h1  = pe3 + 40960;        // 65536
    float* s1  = h1 + 65536;         // 1024
    float* Wr1 = s1 + 1024;          // 65536
    float* h2  = Wr1 + 65536;        // 131072
    float* s2  = h2 + 131072;        // 1024
    float* Wr2 = s2 + 1024;          // 327680
    float* h3  = Wr2 + 327680;       // 327680 (layout spacer)
    unsigned short* h4b   = (unsigned short*)(h3 + 327680);          // 655360 shorts
    unsigned short* Wup2b = (unsigned short*)((float*)h4b + 327680); // 20,480,000 shorts
    float* after = (float*)Wup2b + 10240000;
    unsigned short* Whb = (unsigned short*)after;             // 2,048,000 shorts
    unsigned short* Wlb = Whb + 2048000;                      // 2,048,000 shorts
    float* partA = (float*)(Wlb + 2048000);                   // 3,276,800 floats

    prep_all<<<dim3(4384), 320, 0, stream>>>(W_emb, Whb, Wlb, W_up2, Wup2b,
                                             W_pos1, b_pos1, pe1, W_pos2, b_pos2,
                                             pe2, W_pos3, b_pos3, pe3);
    embA_mfma<<<dim3(16, SPLITS_), 256, 0, stream>>>(x, Whb, Wlb, partA);
    reduceA_kernel<<<dim3(256), 64, 0, stream>>>(partA, b_emb, pe1, h1, s1);
    wr1_kernel<<<dim3(256), 256, 0, stream>>>(W_red, s1, Wr1);
    h2_kernel<<<dim3(1024), 128, 0, stream>>>(h1, Wr1, b_red, pe2, h2, s2);
    wr2_kernel<<<dim3(320), 256, 0, stream>>>(W_red2, s2, Wr2);
    h3h4_kernel<<<dim3(256), 256, 0, stream>>>(h2, Wr2, b_red2, pe3, W_up1,
                                               b_up1, h4b);
    final_mfma_kernel<<<dim3(8, 250), 256, 0, stream>>>(h4b, Wup2b, b_up2, W_fin,
                                                        b_fin, out);
}

// Round 8
// 448.301 us; speedup vs baseline: 1.0494x; 1.0180x over previous
//
#include <hip/hip_runtime.h>
#include <hip/hip_bf16.h>
#include <math.h>

// Problem constants
#define B_  8
#define L_  128
#define V_  32000
#define D_  64
#define R1_ 128
#define R2_ 320
#define UP_ 640
#define SPLITS_ 50   // k-splits for stage A (640 k each)

typedef short bf16x8 __attribute__((ext_vector_type(8)));
typedef float f32x4 __attribute__((ext_vector_type(4)));

#define GLDS16(gp, lp)                                                         \
    __builtin_amdgcn_global_load_lds(                                          \
        (const __attribute__((address_space(1))) void*)(gp),                   \
        (__attribute__((address_space(3))) void*)(lp), 16, 0, 0)

static __device__ inline unsigned short f2bf(float x) {
    __hip_bfloat16 h = __float2bfloat16(x);
    return *reinterpret_cast<unsigned short*>(&h);
}

// hi/lo bf16 split: v ~= hi + lo with rel err ~2^-17
static __device__ inline void split1(float v, unsigned short& h, unsigned short& l) {
    unsigned short hb = f2bf(v);
    float hf = __uint_as_float(((unsigned int)hb) << 16);
    h = hb;
    l = f2bf(v - hf);
}

// ---------------------------------------------------------------------------
// prep_all (round-5 config: Wup2b conversion included).
//   blocks [0,800):      W_emb fp32 -> k-blocked bf16 hi/lo
//   blocks [800,1184):   positional-encoding linears
//   blocks [1184,4384):  Wup2 fp32 -> bf16
__global__ __launch_bounds__(320) void prep_all(const float* __restrict__ Wemb,
                                                unsigned short* __restrict__ Whb,
                                                unsigned short* __restrict__ Wlb,
                                                const float* __restrict__ Wup2,
                                                unsigned short* __restrict__ Wup2b,
                                                const float* __restrict__ W1,
                                                const float* __restrict__ b1,
                                                float* __restrict__ o1,
                                                const float* __restrict__ W2,
                                                const float* __restrict__ b2,
                                                float* __restrict__ o2,
                                                const float* __restrict__ W3,
                                                const float* __restrict__ b3,
                                                float* __restrict__ o3) {
    __shared__ float P[640];
    int bx = blockIdx.x, t = threadIdx.x;
    if (bx < 800) {
        int u = bx * 320 + t;   // 0 .. 256000-1
        int kb = u >> 6, row = u & 63;
        const float* s = Wemb + (size_t)row * 32000 + kb * 8;
        unsigned short h8[8], l8[8];
#pragma unroll
        for (int j = 0; j < 8; ++j) split1(s[j], h8[j], l8[j]);
        *(ushort4*)&Whb[(size_t)u * 8]     = *(ushort4*)&h8[0];
        *(ushort4*)&Whb[(size_t)u * 8 + 4] = *(ushort4*)&h8[4];
        *(ushort4*)&Wlb[(size_t)u * 8]     = *(ushort4*)&l8[0];
        *(ushort4*)&Wlb[(size_t)u * 8 + 4] = *(ushort4*)&l8[4];
    } else if (bx < 1184) {
        int id = bx - 800;
        int l = id & 127;
        int stage = id >> 7;
        const float* W = (stage == 0) ? W1 : (stage == 1) ? W2 : W3;
        const float* bias = (stage == 0) ? b1 : (stage == 1) ? b2 : b3;
        float* out = (stage == 0) ? o1 : (stage == 1) ? o2 : o3;
        int outF = (stage == 0) ? 64 : (stage == 1) ? 128 : 320;
        int dEnc = 2 * outF;
        for (int m = t; m < dEnc; m += 320) {
            int i = m >> 1;
            float ang = (float)l * powf(10000.0f, -2.0f * (float)i / (float)dEnc);
            P[m] = (m & 1) ? cosf(ang) : sinf(ang);
        }
        __syncthreads();
        if (t < outF) {
            float acc = bias[t];
            const float4* w = (const float4*)(W + (size_t)t * dEnc);
            for (int m4 = 0; m4 < dEnc / 4; ++m4) {
                float4 wv = w[m4];
                float4 pv = *(const float4*)&P[m4 * 4];
                acc = fmaf(pv.x, wv.x, acc);
                acc = fmaf(pv.y, wv.y, acc);
                acc = fmaf(pv.z, wv.z, acc);
                acc = fmaf(pv.w, wv.w, acc);
            }
            out[l * outF + t] = fmaxf(acc, 0.f);
        }
    } else {
        const int n4 = (V_ * UP_) / 4;
        int stride = 3200 * 320;
        for (int i = (bx - 1184) * 320 + t; i < n4; i += stride) {
            float4 v = ((const float4*)Wup2)[i];
            ushort4 o;
            o.x = f2bf(v.x); o.y = f2bf(v.y); o.z = f2bf(v.z); o.w = f2bf(v.w);
            ((ushort4*)Wup2b)[i] = o;
        }
    }
}

// ---------------------------------------------------------------------------
// Stage A via MFMA (unchanged).
__global__ __launch_bounds__(256) void embA_mfma(const float* __restrict__ x,
                                                 const unsigned short* __restrict__ Whb,
                                                 const unsigned short* __restrict__ Wlb,
                                                 float* __restrict__ partA) {
    __shared__ short lds[16384];   // 2 x 16 KB
    int t = threadIdx.x;
    int lane = t & 63, w = t >> 6;
    int ln = lane & 15, lg = lane >> 4;
    int rb = blockIdx.x, ks = blockIdx.y;
    int row0 = rb * 64;
    const float* xrow = x + (size_t)(row0 + w * 16 + ln) * 32000;

    f32x4 acc[4];
#pragma unroll
    for (int nt = 0; nt < 4; ++nt) acc[nt] = (f32x4){0.f, 0.f, 0.f, 0.f};

    float4 xc[4], xn[4];
    {
        int kb0 = (ks * 640) >> 3;
#pragma unroll
        for (int s = 0; s < 4; ++s) {
            int ubase = s * 256 + w * 64;
            const unsigned short* arr = (s < 2) ? Whb : Wlb;
            int uu = (s < 2) ? ubase : (ubase - 512);
            const char* gp = (const char*)arr + ((size_t)kb0 * 64 + uu + lane) * 16;
            char* lp = (char*)lds + ((s < 2) ? 0 : 8192) + uu * 16;
            GLDS16(gp, lp);
        }
        const float* bp = xrow + ks * 640 + lg * 8;
        xc[0] = ((const float4*)bp)[0];
        xc[1] = ((const float4*)bp)[1];
        xc[2] = ((const float4*)(bp + 32))[0];
        xc[3] = ((const float4*)(bp + 32))[1];
    }

#pragma unroll 2
    for (int ch = 0; ch < 10; ++ch) {
        __syncthreads();   // drains chunk-ch GLDS16 + x loads
        if (ch < 9) {      // kick chunk ch+1 into the other buffer
            int kb0 = (ks * 640 + (ch + 1) * 64) >> 3;
            int p = (ch + 1) & 1;
#pragma unroll
            for (int s = 0; s < 4; ++s) {
                int ubase = s * 256 + w * 64;
                const unsigned short* arr = (s < 2) ? Whb : Wlb;
                int uu = (s < 2) ? ubase : (ubase - 512);
                const char* gp = (const char*)arr + ((size_t)kb0 * 64 + uu + lane) * 16;
                char* lp = (char*)lds + p * 16384 + ((s < 2) ? 0 : 8192) + uu * 16;
                GLDS16(gp, lp);
            }
            const float* bp = xrow + ks * 640 + (ch + 1) * 64 + lg * 8;
            xn[0] = ((const float4*)bp)[0];
            xn[1] = ((const float4*)bp)[1];
            xn[2] = ((const float4*)(bp + 32))[0];
            xn[3] = ((const float4*)(bp + 32))[1];
        }
        bf16x8 ah[2], al[2];
#pragma unroll
        for (int kstep = 0; kstep < 2; ++kstep) {
            float f[8] = {xc[2 * kstep].x, xc[2 * kstep].y, xc[2 * kstep].z, xc[2 * kstep].w,
                          xc[2 * kstep + 1].x, xc[2 * kstep + 1].y, xc[2 * kstep + 1].z,
                          xc[2 * kstep + 1].w};
            unsigned short h8[8], l8[8];
#pragma unroll
            for (int j = 0; j < 8; ++j) split1(f[j], h8[j], l8[j]);
            ah[kstep] = *(bf16x8*)h8;
            al[kstep] = *(bf16x8*)l8;
        }
        const char* buf = (const char*)lds + (ch & 1) * 16384;
#pragma unroll
        for (int kstep = 0; kstep < 2; ++kstep) {
            int g = kstep * 4 + lg;
#pragma unroll
            for (int nt = 0; nt < 4; ++nt) {
                int nrow = nt * 16 + ln;
                bf16x8 bh = *(const bf16x8*)(buf + (g * 64 + nrow) * 16);
                bf16x8 bl = *(const bf16x8*)(buf + 8192 + (g * 64 + nrow) * 16);
                acc[nt] = __builtin_amdgcn_mfma_f32_16x16x32_bf16(ah[kstep], bh, acc[nt], 0, 0, 0);
                acc[nt] = __builtin_amdgcn_mfma_f32_16x16x32_bf16(ah[kstep], bl, acc[nt], 0, 0, 0);
                acc[nt] = __builtin_amdgcn_mfma_f32_16x16x32_bf16(al[kstep], bh, acc[nt], 0, 0, 0);
            }
        }
#pragma unroll
        for (int i = 0; i < 4; ++i) xc[i] = xn[i];
    }
#pragma unroll
    for (int nt = 0; nt < 4; ++nt)
#pragma unroll
        for (int r = 0; r < 4; ++r)
            partA[((size_t)ks * 1024 + row0 + w * 16 + lg * 4 + r) * 64 + nt * 16 + ln] =
                acc[nt][r];
}

// ---------------------------------------------------------------------------
// reduceA v2 (unchanged).
__global__ __launch_bounds__(64) void reduceA_kernel(const float* __restrict__ partA,
                                                     const float* __restrict__ bemb,
                                                     const float* __restrict__ pe1,
                                                     float* __restrict__ h1,
                                                     float* __restrict__ s1) {
    int lane = threadIdx.x;
    int row = blockIdx.x * 4 + (lane >> 4);
    int d0 = (lane & 15) * 4;
    float4 v = *(const float4*)&bemb[d0];
#pragma unroll 10
    for (int s = 0; s < SPLITS_; ++s) {
        float4 p = *(const float4*)&partA[((size_t)s * 1024 + row) * 64 + d0];
        v.x += p.x; v.y += p.y; v.z += p.z; v.w += p.w;
    }
    float4 pe = *(const float4*)&pe1[(row & 127) * 64 + d0];
    v.x = fmaxf(v.x, 0.f) + pe.x;
    v.y = fmaxf(v.y, 0.f) + pe.y;
    v.z = fmaxf(v.z, 0.f) + pe.z;
    v.w = fmaxf(v.w, 0.f) + pe.w;
    *(float4*)&h1[row * 64 + d0] = v;
    float sum = v.x + v.y + v.z + v.w;
#pragma unroll
    for (int off = 8; off >= 1; off >>= 1) sum += __shfl_down(sum, off);
    if ((lane & 15) == 0) s1[row] = sum;
}

// ---------------------------------------------------------------------------
// wr1 v2 (unchanged).
__global__ __launch_bounds__(256) void wr1_kernel(const float* __restrict__ Wred,
                                                  const float* __restrict__ s1,
                                                  float* __restrict__ Wr1) {
    __shared__ float ss[1024];
    __shared__ float pl[2048];
    int t = threadIdx.x, bb = blockIdx.x;
    for (int i = t; i < 1024; i += 256) ss[i] = s1[i];
    __syncthreads();
    int r = bb >> 1, jh = bb & 1;
    int jj = t & 31, ks = t >> 5;
    int j = jh * 32 + jj;
    float acc[8];
#pragma unroll
    for (int b = 0; b < 8; ++b) acc[b] = 0.f;
    const float* w = Wred + (size_t)r * 8192 + j;
#pragma unroll
    for (int kk = 0; kk < 16; ++kk) {
        int k = ks * 16 + kk;
        float wv = w[k * 64];
#pragma unroll
        for (int b = 0; b < 8; ++b) acc[b] = fmaf(ss[b * 128 + k], wv, acc[b]);
    }
#pragma unroll
    for (int b = 0; b < 8; ++b) pl[t * 8 + b] = acc[b];
    __syncthreads();
    int jj2 = t >> 3, b2 = t & 7;
    float sum = 0.f;
#pragma unroll
    for (int k2 = 0; k2 < 8; ++k2) sum += pl[(k2 * 32 + jj2) * 8 + b2];
    Wr1[((size_t)b2 * 128 + r) * 64 + jh * 32 + jj2] = sum;
}

// ---------------------------------------------------------------------------
// h2 (unchanged).
__global__ __launch_bounds__(128) void h2_kernel(const float* __restrict__ h1,
                                                 const float* __restrict__ Wr1,
                                                 const float* __restrict__ bred,
                                                 const float* __restrict__ pe2,
                                                 float* __restrict__ h2,
                                                 float* __restrict__ s2) {
    __shared__ float hrow[64];
    __shared__ float red[2];
    int row = blockIdx.x;
    int b = row >> 7, i = row & 127;
    int r = threadIdx.x;
    if (r < 64) hrow[r] = h1[row * 64 + r];
    __syncthreads();
    float acc = bred[r];
    const float4* w = (const float4*)(Wr1 + ((size_t)b * 128 + r) * 64);
#pragma unroll
    for (int j4 = 0; j4 < 16; ++j4) {
        float4 wv = w[j4];
        float4 hv = *(const float4*)&hrow[j4 * 4];
        acc = fmaf(hv.x, wv.x, acc);
        acc = fmaf(hv.y, wv.y, acc);
        acc = fmaf(hv.z, wv.z, acc);
        acc = fmaf(hv.w, wv.w, acc);
    }
    float val = fmaxf(acc, 0.f) + pe2[i * 128 + r];
    h2[row * 128 + r] = val;
    float sum = val;
    for (int off = 32; off > 0; off >>= 1) sum += __shfl_down(sum, off);
    if ((r & 63) == 0) red[r >> 6] = sum;
    __syncthreads();
    if (r == 0) s2[row] = red[0] + red[1];
}

// ---------------------------------------------------------------------------
// wr2 v2 (unchanged).
__global__ __launch_bounds__(256) void wr2_kernel(const float* __restrict__ Wred2,
                                                  const float* __restrict__ s2,
                                                  float* __restrict__ Wr2) {
    __shared__ float ss[1024];
    __shared__ float pl[2048];
    int t = threadIdx.x, r = blockIdx.x;
    for (int i = t; i < 1024; i += 256) ss[i] = s2[i];
    __syncthreads();
    int j = t & 127, ks = t >> 7;
    float acc[8];
#pragma unroll
    for (int b = 0; b < 8; ++b) acc[b] = 0.f;
    const float* w = Wred2 + (size_t)r * 16384 + j;
#pragma unroll 16
    for (int kk = 0; kk < 64; ++kk) {
        int k = ks * 64 + kk;
        float wv = w[k * 128];
#pragma unroll
        for (int b = 0; b < 8; ++b) acc[b] = fmaf(ss[b * 128 + k], wv, acc[b]);
    }
#pragma unroll
    for (int b = 0; b < 8; ++b) pl[t * 8 + b] = acc[b];
    __syncthreads();
#pragma unroll
    for (int ii = 0; ii < 4; ++ii) {
        int idx = t * 4 + ii;
        int j2 = idx >> 3, b2 = idx & 7;
        float sum = pl[j2 * 8 + b2] + pl[(128 + j2) * 8 + b2];
        Wr2[((size_t)b2 * 320 + r) * 128 + j2] = sum;
    }
}

// ---------------------------------------------------------------------------
// h3+h4 fused (unchanged).
__global__ __launch_bounds__(256) void h3h4_kernel(const float* __restrict__ h2,
                                                   const float* __restrict__ Wr2,
                                                   const float* __restrict__ bred2,
                                                   const float* __restrict__ pe3,
                                                   const float* __restrict__ Wup1,
                                                   const float* __restrict__ bup1,
                                                   unsigned short* __restrict__ h4b) {
    __shared__ float h2r[512];    // 4 rows x 128
    __shared__ float hsT[1280];   // hsT[r*4+q] = h3[row0+q][r]
    int t = threadIdx.x;
    int row0 = blockIdx.x * 4;
    int b = row0 >> 7;
    h2r[t] = h2[(size_t)row0 * 128 + t];
    h2r[t + 256] = h2[(size_t)row0 * 128 + t + 256];
    __syncthreads();
    int i_ = row0 & 127;
    for (int r = t; r < 320; r += 256) {
        const float4* w = (const float4*)(Wr2 + ((size_t)b * 320 + r) * 128);
        float a0 = bred2[r], a1 = a0, a2 = a0, a3 = a0;
#pragma unroll
        for (int j4 = 0; j4 < 32; ++j4) {
            float4 wv = w[j4];
            float4 q0 = *(const float4*)&h2r[0 * 128 + j4 * 4];
            float4 q1 = *(const float4*)&h2r[1 * 128 + j4 * 4];
            float4 q2 = *(const float4*)&h2r[2 * 128 + j4 * 4];
            float4 q3 = *(const float4*)&h2r[3 * 128 + j4 * 4];
            a0 = fmaf(q0.x, wv.x, a0); a0 = fmaf(q0.y, wv.y, a0);
            a0 = fmaf(q0.z, wv.z, a0); a0 = fmaf(q0.w, wv.w, a0);
            a1 = fmaf(q1.x, wv.x, a1); a1 = fmaf(q1.y, wv.y, a1);
            a1 = fmaf(q1.z, wv.z, a1); a1 = fmaf(q1.w, wv.w, a1);
            a2 = fmaf(q2.x, wv.x, a2); a2 = fmaf(q2.y, wv.y, a2);
            a2 = fmaf(q2.z, wv.z, a2); a2 = fmaf(q2.w, wv.w, a2);
            a3 = fmaf(q3.x, wv.x, a3); a3 = fmaf(q3.y, wv.y, a3);
            a3 = fmaf(q3.z, wv.z, a3); a3 = fmaf(q3.w, wv.w, a3);
        }
        hsT[r * 4 + 0] = fmaxf(a0, 0.f) + pe3[(i_ + 0) * 320 + r];
        hsT[r * 4 + 1] = fmaxf(a1, 0.f) + pe3[(i_ + 1) * 320 + r];
        hsT[r * 4 + 2] = fmaxf(a2, 0.f) + pe3[(i_ + 2) * 320 + r];
        hsT[r * 4 + 3] = fmaxf(a3, 0.f) + pe3[(i_ + 3) * 320 + r];
    }
    __syncthreads();
    for (int u = t; u < 640; u += 256) {
        float acc[4] = {0.f, 0.f, 0.f, 0.f};
        const float4* w = (const float4*)(Wup1 + (size_t)u * 320);
#pragma unroll 2
        for (int j4 = 0; j4 < 80; ++j4) {
            float4 wv = w[j4];
#pragma unroll
            for (int e = 0; e < 4; ++e) {
                float wc = (e == 0) ? wv.x : (e == 1) ? wv.y : (e == 2) ? wv.z : wv.w;
                float4 hv = *(const float4*)&hsT[(j4 * 4 + e) * 4];
                acc[0] = fmaf(hv.x, wc, acc[0]);
                acc[1] = fmaf(hv.y, wc, acc[1]);
                acc[2] = fmaf(hv.z, wc, acc[2]);
                acc[3] = fmaf(hv.w, wc, acc[3]);
            }
        }
        float bias = bup1[u];
#pragma unroll
        for (int q = 0; q < 4; ++q)
            h4b[(size_t)(row0 + q) * 640 + u] = f2bf(fmaxf(acc[q] + bias, 0.f));
    }
}

// ---------------------------------------------------------------------------
// final MFMA (round-5 version, best measured ~75 us): bf16 operands, BK=32
// dbuf, 512 thr (8 waves), 2-batch tile 128v x (2b x 128l), grid (4,250),
// conflict-free 128-B-row interleaved LDS layout (0 conflicts measured):
//   A: 64 phys rows x 128 B; phys row pr holds v-rows {2pr, 2pr+1};
//      unit = ((rA&1)<<2 | lg) ^ (pr&7)
//   B: 128 phys rows x 128 B; row r holds B0-row r | B1-row r;
//      unit = (bl_<<2 | lg) ^ (r&7)
// 2 x 24 KB + redbuf -> 3 blocks/CU = 24 waves/CU.
__global__ __launch_bounds__(512) void final_mfma_kernel(
    const unsigned short* __restrict__ h4b,
    const unsigned short* __restrict__ Wup2b,
    const float* __restrict__ bup2,
    const float* __restrict__ Wfin,
    const float* __restrict__ bfin,
    float* __restrict__ out) {
    __shared__ short tile[2][12288];       // 2 x 24 KB buffers
    __shared__ float redbuf[2][2][128];    // [b_local][l_half][v]

    int t = threadIdx.x;
    int lane = t & 63;
    int w = t >> 6;                 // 0..7
    int wv = w >> 2;                // v-half 0..1
    int wq = w & 3;                 // n-quadrant: b_local = wq>>1, l_half = wq&1
    int bl_ = wq >> 1, lh = wq & 1;
    int ln = lane & 15, lg = lane >> 4;
    int b0 = blockIdx.x * 2;
    int v0 = blockIdx.y * 128;

    f32x4 acc[4][4];
#pragma unroll
    for (int mt = 0; mt < 4; ++mt)
#pragma unroll
        for (int nt = 0; nt < 4; ++nt) acc[mt][nt] = (f32x4){0.f, 0.f, 0.f, 0.f};

    // stage chunk ch (32 k) into buffer p; LDS dest linear, source carries the
    // inverse of the read-side unit swizzle (same involution).
    auto stage = [&](int ch, int p) {
#pragma unroll
        for (int s = 0; s < 3; ++s) {
            int F = (w * 3 + s) * 1024 + lane * 16;     // byte offset in 24 KB
            const char* gp;
            if (F < 8192) {                              // A region
                int pr = F >> 7;                         // phys row 0..63
                int u = (F >> 4) & 7;                    // phys unit
                int l = u ^ (pr & 7);                    // logical
                int o = l >> 2, g = l & 3;
                gp = (const char*)Wup2b +
                     (((size_t)(v0 + 2 * pr + o)) * 640 + (size_t)(ch * 32 + g * 8)) * 2;
            } else {                                     // B region
                int FF = F - 8192;
                int pr = FF >> 7;                        // phys row 0..127
                int u = (FF >> 4) & 7;
                int l = u ^ (pr & 7);
                int region = l >> 2, g = l & 3;
                gp = (const char*)h4b +
                     (((size_t)(b0 + region) * 128 + pr) * 640 +
                      (size_t)(ch * 32 + g * 8)) * 2;
            }
            char* lp = (char*)&tile[p][0] + (w * 3 + s) * 1024;   // wave-uniform
            GLDS16(gp, lp);
        }
    };

    stage(0, 0);

#pragma unroll 2
    for (int ch = 0; ch < 20; ++ch) {
        __syncthreads();                  // drains chunk-ch GLDS16
        if (ch < 19) stage(ch + 1, (ch + 1) & 1);
        const char* buf = (const char*)&tile[ch & 1][0];
        bf16x8 aF[4], bF[4];
#pragma unroll
        for (int mt = 0; mt < 4; ++mt) {
            int rA = wv * 64 + mt * 16 + ln;
            int pr = rA >> 1;
            int unit = (((rA & 1) << 2) | lg) ^ (pr & 7);
            aF[mt] = *(const bf16x8*)(buf + pr * 128 + unit * 16);
        }
#pragma unroll
        for (int nt = 0; nt < 4; ++nt) {
            int rB = lh * 64 + nt * 16 + ln;
            int unit = ((bl_ << 2) | lg) ^ (rB & 7);
            bF[nt] = *(const bf16x8*)(buf + 8192 + rB * 128 + unit * 16);
        }
#pragma unroll
        for (int mt = 0; mt < 4; ++mt)
#pragma unroll
            for (int nt = 0; nt < 4; ++nt)
                acc[mt][nt] = __builtin_amdgcn_mfma_f32_16x16x32_bf16(
                    aF[mt], bF[nt], acc[mt][nt], 0, 0, 0);
    }

    // Epilogue: C/D layout col(l)=lane&15, row(v)=(lane>>4)*4+reg
    float bfin0 = bfin[0];
#pragma unroll
    for (int mt = 0; mt < 4; ++mt) {
        float bu[4];
#pragma unroll
        for (int r = 0; r < 4; ++r)
            bu[r] = bup2[v0 + wv * 64 + mt * 16 + lg * 4 + r];
        float part[4] = {0.f, 0.f, 0.f, 0.f};
#pragma unroll
        for (int nt = 0; nt < 4; ++nt) {
            float wf = Wfin[lh * 64 + nt * 16 + ln];
#pragma unroll
            for (int r = 0; r < 4; ++r)
                part[r] += wf * fmaxf(acc[mt][nt][r] + bu[r], 0.f);
        }
#pragma unroll
        for (int off = 8; off >= 1; off >>= 1)
#pragma unroll
            for (int r = 0; r < 4; ++r) part[r] += __shfl_xor(part[r], off, 64);
        if (ln == 0) {
#pragma unroll
            for (int r = 0; r < 4; ++r)
                redbuf[bl_][lh][wv * 64 + mt * 16 + lg * 4 + r] = part[r];
        }
    }
    __syncthreads();
    if (t < 256) {
        int bb = t >> 7, v = t & 127;
        float vsum = redbuf[bb][0][v] + redbuf[bb][1][v] + bfin0;
        out[(size_t)(b0 + bb) * 32000 + v0 + v] = fmaxf(vsum, 0.f);
    }
}

// ---------------------------------------------------------------------------
extern "C" void kernel_launch(void* const* d_in, const int* in_sizes, int n_in,
                              void* d_out, int out_size, void* d_ws, size_t ws_size,
                              hipStream_t stream) {
    const float* x      = (const float*)d_in[0];
    const float* W_emb  = (const float*)d_in[1];
    const float* b_emb  = (const float*)d_in[2];
    const float* W_pos1 = (const float*)d_in[3];
    const float* b_pos1 = (const float*)d_in[4];
    const float* W_red  = (const float*)d_in[5];
    const float* b_red  = (const float*)d_in[6];
    const float* W_pos2 = (const float*)d_in[7];
    const float* b_pos2 = (const float*)d_in[8];
    const float* W_red2 = (const float*)d_in[9];
    const float* b_red2 = (const float*)d_in[10];
    const float* W_pos3 = (const float*)d_in[11];
    const float* b_pos3 = (const float*)d_in[12];
    const float* W_up1  = (const float*)d_in[13];
    const float* b_up1  = (const float*)d_in[14];
    const float* W_up2  = (const float*)d_in[15];
    const float* b_up2  = (const float*)d_in[16];
    const float* W_fin  = (const float*)d_in[17];
    const float* b_fin  = (const float*)d_in[18];
    float* out = (float*)d_out;

    float* ws  = (float*)d_ws;
    float* pe1 = ws;                 // 8192
    float* pe2 = pe1 + 8192;         // 16384
    float* pe3 = pe2 + 16384;        // 40960
    float* h1  = pe3 + 40960;        // 65536
    float* s1  = h1 + 65536;         // 1024
    float* Wr1 = s1 + 1024;          // 65536
    float* h2  = Wr1 + 65536;        // 131072
    float* s2  = h2 + 131072;        // 1024
    float* Wr2 = s2 + 1024;          // 327680
    float* h3  = Wr2 + 327680;       // 327680 (layout spacer)
    unsigned short* h4b   = (unsigned short*)(h3 + 327680);          // 655360 shorts
    unsigned short* Wup2b = (unsigned short*)((float*)h4b + 327680); // 20,480,000 shorts
    float* after = (float*)Wup2b + 10240000;
    unsigned short* Whb = (unsigned short*)after;             // 2,048,000 shorts
    unsigned short* Wlb = Whb + 2048000;                      // 2,048,000 shorts
    float* partA = (float*)(Wlb + 2048000);                   // 3,276,800 floats

    prep_all<<<dim3(4384), 320, 0, stream>>>(W_emb, Whb, Wlb, W_up2, Wup2b,
                                             W_pos1, b_pos1, pe1, W_pos2, b_pos2,
                                             pe2, W_pos3, b_pos3, pe3);
    embA_mfma<<<dim3(16, SPLITS_), 256, 0, stream>>>(x, Whb, Wlb, partA);
    reduceA_kernel<<<dim3(256), 64, 0, stream>>>(partA, b_emb, pe1, h1, s1);
    wr1_kernel<<<dim3(256), 256, 0, stream>>>(W_red, s1, Wr1);
    h2_kernel<<<dim3(1024), 128, 0, stream>>>(h1, Wr1, b_red, pe2, h2, s2);
    wr2_kernel<<<dim3(320), 256, 0, stream>>>(W_red2, s2, Wr2);
    h3h4_kernel<<<dim3(256), 256, 0, stream>>>(h2, Wr2, b_red2, pe3, W_up1,
                                               b_up1, h4b);
    final_mfma_kernel<<<dim3(4, 250), 512, 0, stream>>>(h4b, Wup2b, b_up2, W_fin,
                                                        b_fin, out);
}

// Round 9
// 445.414 us; speedup vs baseline: 1.0562x; 1.0065x over previous
//
#include <hip/hip_runtime.h>
#include <hip/hip_bf16.h>
#include <math.h>

// Problem constants
#define B_  8
#define L_  128
#define V_  32000
#define D_  64
#define R1_ 128
#define R2_ 320
#define UP_ 640
#define SPLITS_ 50   // k-splits for stage A (640 k each)

typedef short bf16x8 __attribute__((ext_vector_type(8)));
typedef float f32x4 __attribute__((ext_vector_type(4)));

#define GLDS16(gp, lp)                                                         \
    __builtin_amdgcn_global_load_lds(                                          \
        (const __attribute__((address_space(1))) void*)(gp),                   \
        (__attribute__((address_space(3))) void*)(lp), 16, 0, 0)

static __device__ inline unsigned short f2bf(float x) {
    __hip_bfloat16 h = __float2bfloat16(x);
    return *reinterpret_cast<unsigned short*>(&h);
}

// hi/lo bf16 split: v ~= hi + lo with rel err ~2^-17
static __device__ inline void split1(float v, unsigned short& h, unsigned short& l) {
    unsigned short hb = f2bf(v);
    float hf = __uint_as_float(((unsigned int)hb) << 16);
    h = hb;
    l = f2bf(v - hf);
}

// ---------------------------------------------------------------------------
// prep_all (round-5 config: Wup2b conversion included).
__global__ __launch_bounds__(320) void prep_all(const float* __restrict__ Wemb,
                                                unsigned short* __restrict__ Whb,
                                                unsigned short* __restrict__ Wlb,
                                                const float* __restrict__ Wup2,
                                                unsigned short* __restrict__ Wup2b,
                                                const float* __restrict__ W1,
                                                const float* __restrict__ b1,
                                                float* __restrict__ o1,
                                                const float* __restrict__ W2,
                                                const float* __restrict__ b2,
                                                float* __restrict__ o2,
                                                const float* __restrict__ W3,
                                                const float* __restrict__ b3,
                                                float* __restrict__ o3) {
    __shared__ float P[640];
    int bx = blockIdx.x, t = threadIdx.x;
    if (bx < 800) {
        int u = bx * 320 + t;   // 0 .. 256000-1
        int kb = u >> 6, row = u & 63;
        const float* s = Wemb + (size_t)row * 32000 + kb * 8;
        unsigned short h8[8], l8[8];
#pragma unroll
        for (int j = 0; j < 8; ++j) split1(s[j], h8[j], l8[j]);
        *(ushort4*)&Whb[(size_t)u * 8]     = *(ushort4*)&h8[0];
        *(ushort4*)&Whb[(size_t)u * 8 + 4] = *(ushort4*)&h8[4];
        *(ushort4*)&Wlb[(size_t)u * 8]     = *(ushort4*)&l8[0];
        *(ushort4*)&Wlb[(size_t)u * 8 + 4] = *(ushort4*)&l8[4];
    } else if (bx < 1184) {
        int id = bx - 800;
        int l = id & 127;
        int stage = id >> 7;
        const float* W = (stage == 0) ? W1 : (stage == 1) ? W2 : W3;
        const float* bias = (stage == 0) ? b1 : (stage == 1) ? b2 : b3;
        float* out = (stage == 0) ? o1 : (stage == 1) ? o2 : o3;
        int outF = (stage == 0) ? 64 : (stage == 1) ? 128 : 320;
        int dEnc = 2 * outF;
        for (int m = t; m < dEnc; m += 320) {
            int i = m >> 1;
            float ang = (float)l * powf(10000.0f, -2.0f * (float)i / (float)dEnc);
            P[m] = (m & 1) ? cosf(ang) : sinf(ang);
        }
        __syncthreads();
        if (t < outF) {
            float acc = bias[t];
            const float4* w = (const float4*)(W + (size_t)t * dEnc);
            for (int m4 = 0; m4 < dEnc / 4; ++m4) {
                float4 wv = w[m4];
                float4 pv = *(const float4*)&P[m4 * 4];
                acc = fmaf(pv.x, wv.x, acc);
                acc = fmaf(pv.y, wv.y, acc);
                acc = fmaf(pv.z, wv.z, acc);
                acc = fmaf(pv.w, wv.w, acc);
            }
            out[l * outF + t] = fmaxf(acc, 0.f);
        }
    } else {
        const int n4 = (V_ * UP_) / 4;
        int stride = 3200 * 320;
        for (int i = (bx - 1184) * 320 + t; i < n4; i += stride) {
            float4 v = ((const float4*)Wup2)[i];
            ushort4 o;
            o.x = f2bf(v.x); o.y = f2bf(v.y); o.z = f2bf(v.z); o.w = f2bf(v.w);
            ((ushort4*)Wup2b)[i] = o;
        }
    }
}

// ---------------------------------------------------------------------------
// Stage A via MFMA (unchanged).
__global__ __launch_bounds__(256) void embA_mfma(const float* __restrict__ x,
                                                 const unsigned short* __restrict__ Whb,
                                                 const unsigned short* __restrict__ Wlb,
                                                 float* __restrict__ partA) {
    __shared__ short lds[16384];   // 2 x 16 KB
    int t = threadIdx.x;
    int lane = t & 63, w = t >> 6;
    int ln = lane & 15, lg = lane >> 4;
    int rb = blockIdx.x, ks = blockIdx.y;
    int row0 = rb * 64;
    const float* xrow = x + (size_t)(row0 + w * 16 + ln) * 32000;

    f32x4 acc[4];
#pragma unroll
    for (int nt = 0; nt < 4; ++nt) acc[nt] = (f32x4){0.f, 0.f, 0.f, 0.f};

    float4 xc[4], xn[4];
    {
        int kb0 = (ks * 640) >> 3;
#pragma unroll
        for (int s = 0; s < 4; ++s) {
            int ubase = s * 256 + w * 64;
            const unsigned short* arr = (s < 2) ? Whb : Wlb;
            int uu = (s < 2) ? ubase : (ubase - 512);
            const char* gp = (const char*)arr + ((size_t)kb0 * 64 + uu + lane) * 16;
            char* lp = (char*)lds + ((s < 2) ? 0 : 8192) + uu * 16;
            GLDS16(gp, lp);
        }
        const float* bp = xrow + ks * 640 + lg * 8;
        xc[0] = ((const float4*)bp)[0];
        xc[1] = ((const float4*)bp)[1];
        xc[2] = ((const float4*)(bp + 32))[0];
        xc[3] = ((const float4*)(bp + 32))[1];
    }

#pragma unroll 2
    for (int ch = 0; ch < 10; ++ch) {
        __syncthreads();   // drains chunk-ch GLDS16 + x loads
        if (ch < 9) {      // kick chunk ch+1 into the other buffer
            int kb0 = (ks * 640 + (ch + 1) * 64) >> 3;
            int p = (ch + 1) & 1;
#pragma unroll
            for (int s = 0; s < 4; ++s) {
                int ubase = s * 256 + w * 64;
                const unsigned short* arr = (s < 2) ? Whb : Wlb;
                int uu = (s < 2) ? ubase : (ubase - 512);
                const char* gp = (const char*)arr + ((size_t)kb0 * 64 + uu + lane) * 16;
                char* lp = (char*)lds + p * 16384 + ((s < 2) ? 0 : 8192) + uu * 16;
                GLDS16(gp, lp);
            }
            const float* bp = xrow + ks * 640 + (ch + 1) * 64 + lg * 8;
            xn[0] = ((const float4*)bp)[0];
            xn[1] = ((const float4*)bp)[1];
            xn[2] = ((const float4*)(bp + 32))[0];
            xn[3] = ((const float4*)(bp + 32))[1];
        }
        bf16x8 ah[2], al[2];
#pragma unroll
        for (int kstep = 0; kstep < 2; ++kstep) {
            float f[8] = {xc[2 * kstep].x, xc[2 * kstep].y, xc[2 * kstep].z, xc[2 * kstep].w,
                          xc[2 * kstep + 1].x, xc[2 * kstep + 1].y, xc[2 * kstep + 1].z,
                          xc[2 * kstep + 1].w};
            unsigned short h8[8], l8[8];
#pragma unroll
            for (int j = 0; j < 8; ++j) split1(f[j], h8[j], l8[j]);
            ah[kstep] = *(bf16x8*)h8;
            al[kstep] = *(bf16x8*)l8;
        }
        const char* buf = (const char*)lds + (ch & 1) * 16384;
#pragma unroll
        for (int kstep = 0; kstep < 2; ++kstep) {
            int g = kstep * 4 + lg;
#pragma unroll
            for (int nt = 0; nt < 4; ++nt) {
                int nrow = nt * 16 + ln;
                bf16x8 bh = *(const bf16x8*)(buf + (g * 64 + nrow) * 16);
                bf16x8 bl = *(const bf16x8*)(buf + 8192 + (g * 64 + nrow) * 16);
                acc[nt] = __builtin_amdgcn_mfma_f32_16x16x32_bf16(ah[kstep], bh, acc[nt], 0, 0, 0);
                acc[nt] = __builtin_amdgcn_mfma_f32_16x16x32_bf16(ah[kstep], bl, acc[nt], 0, 0, 0);
                acc[nt] = __builtin_amdgcn_mfma_f32_16x16x32_bf16(al[kstep], bh, acc[nt], 0, 0, 0);
            }
        }
#pragma unroll
        for (int i = 0; i < 4; ++i) xc[i] = xn[i];
    }
#pragma unroll
    for (int nt = 0; nt < 4; ++nt)
#pragma unroll
        for (int r = 0; r < 4; ++r)
            partA[((size_t)ks * 1024 + row0 + w * 16 + lg * 4 + r) * 64 + nt * 16 + ln] =
                acc[nt][r];
}

// ---------------------------------------------------------------------------
// reduceA v2 (unchanged).
__global__ __launch_bounds__(64) void reduceA_kernel(const float* __restrict__ partA,
                                                     const float* __restrict__ bemb,
                                                     const float* __restrict__ pe1,
                                                     float* __restrict__ h1,
                                                     float* __restrict__ s1) {
    int lane = threadIdx.x;
    int row = blockIdx.x * 4 + (lane >> 4);
    int d0 = (lane & 15) * 4;
    float4 v = *(const float4*)&bemb[d0];
#pragma unroll 10
    for (int s = 0; s < SPLITS_; ++s) {
        float4 p = *(const float4*)&partA[((size_t)s * 1024 + row) * 64 + d0];
        v.x += p.x; v.y += p.y; v.z += p.z; v.w += p.w;
    }
    float4 pe = *(const float4*)&pe1[(row & 127) * 64 + d0];
    v.x = fmaxf(v.x, 0.f) + pe.x;
    v.y = fmaxf(v.y, 0.f) + pe.y;
    v.z = fmaxf(v.z, 0.f) + pe.z;
    v.w = fmaxf(v.w, 0.f) + pe.w;
    *(float4*)&h1[row * 64 + d0] = v;
    float sum = v.x + v.y + v.z + v.w;
#pragma unroll
    for (int off = 8; off >= 1; off >>= 1) sum += __shfl_down(sum, off);
    if ((lane & 15) == 0) s1[row] = sum;
}

// ---------------------------------------------------------------------------
// wr1 v2 (unchanged).
__global__ __launch_bounds__(256) void wr1_kernel(const float* __restrict__ Wred,
                                                  const float* __restrict__ s1,
                                                  float* __restrict__ Wr1) {
    __shared__ float ss[1024];
    __shared__ float pl[2048];
    int t = threadIdx.x, bb = blockIdx.x;
    for (int i = t; i < 1024; i += 256) ss[i] = s1[i];
    __syncthreads();
    int r = bb >> 1, jh = bb & 1;
    int jj = t & 31, ks = t >> 5;
    int j = jh * 32 + jj;
    float acc[8];
#pragma unroll
    for (int b = 0; b < 8; ++b) acc[b] = 0.f;
    const float* w = Wred + (size_t)r * 8192 + j;
#pragma unroll
    for (int kk = 0; kk < 16; ++kk) {
        int k = ks * 16 + kk;
        float wv = w[k * 64];
#pragma unroll
        for (int b = 0; b < 8; ++b) acc[b] = fmaf(ss[b * 128 + k], wv, acc[b]);
    }
#pragma unroll
    for (int b = 0; b < 8; ++b) pl[t * 8 + b] = acc[b];
    __syncthreads();
    int jj2 = t >> 3, b2 = t & 7;
    float sum = 0.f;
#pragma unroll
    for (int k2 = 0; k2 < 8; ++k2) sum += pl[(k2 * 32 + jj2) * 8 + b2];
    Wr1[((size_t)b2 * 128 + r) * 64 + jh * 32 + jj2] = sum;
}

// ---------------------------------------------------------------------------
// h2 (unchanged).
__global__ __launch_bounds__(128) void h2_kernel(const float* __restrict__ h1,
                                                 const float* __restrict__ Wr1,
                                                 const float* __restrict__ bred,
                                                 const float* __restrict__ pe2,
                                                 float* __restrict__ h2,
                                                 float* __restrict__ s2) {
    __shared__ float hrow[64];
    __shared__ float red[2];
    int row = blockIdx.x;
    int b = row >> 7, i = row & 127;
    int r = threadIdx.x;
    if (r < 64) hrow[r] = h1[row * 64 + r];
    __syncthreads();
    float acc = bred[r];
    const float4* w = (const float4*)(Wr1 + ((size_t)b * 128 + r) * 64);
#pragma unroll
    for (int j4 = 0; j4 < 16; ++j4) {
        float4 wv = w[j4];
        float4 hv = *(const float4*)&hrow[j4 * 4];
        acc = fmaf(hv.x, wv.x, acc);
        acc = fmaf(hv.y, wv.y, acc);
        acc = fmaf(hv.z, wv.z, acc);
        acc = fmaf(hv.w, wv.w, acc);
    }
    float val = fmaxf(acc, 0.f) + pe2[i * 128 + r];
    h2[row * 128 + r] = val;
    float sum = val;
    for (int off = 32; off > 0; off >>= 1) sum += __shfl_down(sum, off);
    if ((r & 63) == 0) red[r >> 6] = sum;
    __syncthreads();
    if (r == 0) s2[row] = red[0] + red[1];
}

// ---------------------------------------------------------------------------
// wr2 v2 (unchanged).
__global__ __launch_bounds__(256) void wr2_kernel(const float* __restrict__ Wred2,
                                                  const float* __restrict__ s2,
                                                  float* __restrict__ Wr2) {
    __shared__ float ss[1024];
    __shared__ float pl[2048];
    int t = threadIdx.x, r = blockIdx.x;
    for (int i = t; i < 1024; i += 256) ss[i] = s2[i];
    __syncthreads();
    int j = t & 127, ks = t >> 7;
    float acc[8];
#pragma unroll
    for (int b = 0; b < 8; ++b) acc[b] = 0.f;
    const float* w = Wred2 + (size_t)r * 16384 + j;
#pragma unroll 16
    for (int kk = 0; kk < 64; ++kk) {
        int k = ks * 64 + kk;
        float wv = w[k * 128];
#pragma unroll
        for (int b = 0; b < 8; ++b) acc[b] = fmaf(ss[b * 128 + k], wv, acc[b]);
    }
#pragma unroll
    for (int b = 0; b < 8; ++b) pl[t * 8 + b] = acc[b];
    __syncthreads();
#pragma unroll
    for (int ii = 0; ii < 4; ++ii) {
        int idx = t * 4 + ii;
        int j2 = idx >> 3, b2 = idx & 7;
        float sum = pl[j2 * 8 + b2] + pl[(128 + j2) * 8 + b2];
        Wr2[((size_t)b2 * 320 + r) * 128 + j2] = sum;
    }
}

// ---------------------------------------------------------------------------
// h3+h4 fused (unchanged).
__global__ __launch_bounds__(256) void h3h4_kernel(const float* __restrict__ h2,
                                                   const float* __restrict__ Wr2,
                                                   const float* __restrict__ bred2,
                                                   const float* __restrict__ pe3,
                                                   const float* __restrict__ Wup1,
                                                   const float* __restrict__ bup1,
                                                   unsigned short* __restrict__ h4b) {
    __shared__ float h2r[512];    // 4 rows x 128
    __shared__ float hsT[1280];   // hsT[r*4+q] = h3[row0+q][r]
    int t = threadIdx.x;
    int row0 = blockIdx.x * 4;
    int b = row0 >> 7;
    h2r[t] = h2[(size_t)row0 * 128 + t];
    h2r[t + 256] = h2[(size_t)row0 * 128 + t + 256];
    __syncthreads();
    int i_ = row0 & 127;
    for (int r = t; r < 320; r += 256) {
        const float4* w = (const float4*)(Wr2 + ((size_t)b * 320 + r) * 128);
        float a0 = bred2[r], a1 = a0, a2 = a0, a3 = a0;
#pragma unroll
        for (int j4 = 0; j4 < 32; ++j4) {
            float4 wv = w[j4];
            float4 q0 = *(const float4*)&h2r[0 * 128 + j4 * 4];
            float4 q1 = *(const float4*)&h2r[1 * 128 + j4 * 4];
            float4 q2 = *(const float4*)&h2r[2 * 128 + j4 * 4];
            float4 q3 = *(const float4*)&h2r[3 * 128 + j4 * 4];
            a0 = fmaf(q0.x, wv.x, a0); a0 = fmaf(q0.y, wv.y, a0);
            a0 = fmaf(q0.z, wv.z, a0); a0 = fmaf(q0.w, wv.w, a0);
            a1 = fmaf(q1.x, wv.x, a1); a1 = fmaf(q1.y, wv.y, a1);
            a1 = fmaf(q1.z, wv.z, a1); a1 = fmaf(q1.w, wv.w, a1);
            a2 = fmaf(q2.x, wv.x, a2); a2 = fmaf(q2.y, wv.y, a2);
            a2 = fmaf(q2.z, wv.z, a2); a2 = fmaf(q2.w, wv.w, a2);
            a3 = fmaf(q3.x, wv.x, a3); a3 = fmaf(q3.y, wv.y, a3);
            a3 = fmaf(q3.z, wv.z, a3); a3 = fmaf(q3.w, wv.w, a3);
        }
        hsT[r * 4 + 0] = fmaxf(a0, 0.f) + pe3[(i_ + 0) * 320 + r];
        hsT[r * 4 + 1] = fmaxf(a1, 0.f) + pe3[(i_ + 1) * 320 + r];
        hsT[r * 4 + 2] = fmaxf(a2, 0.f) + pe3[(i_ + 2) * 320 + r];
        hsT[r * 4 + 3] = fmaxf(a3, 0.f) + pe3[(i_ + 3) * 320 + r];
    }
    __syncthreads();
    for (int u = t; u < 640; u += 256) {
        float acc[4] = {0.f, 0.f, 0.f, 0.f};
        const float4* w = (const float4*)(Wup1 + (size_t)u * 320);
#pragma unroll 2
        for (int j4 = 0; j4 < 80; ++j4) {
            float4 wv = w[j4];
#pragma unroll
            for (int e = 0; e < 4; ++e) {
                float wc = (e == 0) ? wv.x : (e == 1) ? wv.y : (e == 2) ? wv.z : wv.w;
                float4 hv = *(const float4*)&hsT[(j4 * 4 + e) * 4];
                acc[0] = fmaf(hv.x, wc, acc[0]);
                acc[1] = fmaf(hv.y, wc, acc[1]);
                acc[2] = fmaf(hv.z, wc, acc[2]);
                acc[3] = fmaf(hv.w, wc, acc[3]);
            }
        }
        float bias = bup1[u];
#pragma unroll
        for (int q = 0; q < 4; ++q)
            h4b[(size_t)(row0 + q) * 640 + u] = f2bf(fmaxf(acc[q] + bias, 0.f));
    }
}

// ---------------------------------------------------------------------------
// final MFMA (round-5 core, XCD-grouped grid): 1024 1-D blocks; the 4 sibling
// b-blocks of each v-panel get bids congruent mod 8 -> same XCD -> the 164 KB
// Wup2b panel is fetched once into that XCD's L2 and reused 4x (was: 4 XCDs
// x 1 fetch each = 164 MB total A traffic; now ~41 MB).
// Kernel internals identical to round 5/8 (proven conflict-free layout).
__global__ __launch_bounds__(512) void final_mfma_kernel(
    const unsigned short* __restrict__ h4b,
    const unsigned short* __restrict__ Wup2b,
    const float* __restrict__ bup2,
    const float* __restrict__ Wfin,
    const float* __restrict__ bfin,
    float* __restrict__ out) {
    __shared__ short tile[2][12288];       // 2 x 24 KB buffers
    __shared__ float redbuf[2][2][128];    // [b_local][l_half][v]

    // XCD-grouped decode: bid = r + 8*(j + 4*g); panel vp = g*8 + r; b0 = 2j.
    int bid = blockIdx.x;
    int r_ = bid & 7;
    int q_ = bid >> 3;
    int j_ = q_ & 3;
    int g_ = q_ >> 2;
    int vp = g_ * 8 + r_;
    if (vp >= 250) return;
    int b0 = j_ * 2;
    int v0 = vp * 128;

    int t = threadIdx.x;
    int lane = t & 63;
    int w = t >> 6;                 // 0..7
    int wv = w >> 2;                // v-half 0..1
    int wq = w & 3;                 // n-quadrant: b_local = wq>>1, l_half = wq&1
    int bl_ = wq >> 1, lh = wq & 1;
    int ln = lane & 15, lg = lane >> 4;

    f32x4 acc[4][4];
#pragma unroll
    for (int mt = 0; mt < 4; ++mt)
#pragma unroll
        for (int nt = 0; nt < 4; ++nt) acc[mt][nt] = (f32x4){0.f, 0.f, 0.f, 0.f};

    // stage chunk ch (32 k) into buffer p; LDS dest linear, source carries the
    // inverse of the read-side unit swizzle (same involution).
    auto stage = [&](int ch, int p) {
#pragma unroll
        for (int s = 0; s < 3; ++s) {
            int F = (w * 3 + s) * 1024 + lane * 16;     // byte offset in 24 KB
            const char* gp;
            if (F < 8192) {                              // A region
                int pr = F >> 7;                         // phys row 0..63
                int u = (F >> 4) & 7;                    // phys unit
                int l = u ^ (pr & 7);                    // logical
                int o = l >> 2, g = l & 3;
                gp = (const char*)Wup2b +
                     (((size_t)(v0 + 2 * pr + o)) * 640 + (size_t)(ch * 32 + g * 8)) * 2;
            } else {                                     // B region
                int FF = F - 8192;
                int pr = FF >> 7;                        // phys row 0..127
                int u = (FF >> 4) & 7;
                int l = u ^ (pr & 7);
                int region = l >> 2, g = l & 3;
                gp = (const char*)h4b +
                     (((size_t)(b0 + region) * 128 + pr) * 640 +
                      (size_t)(ch * 32 + g * 8)) * 2;
            }
            char* lp = (char*)&tile[p][0] + (w * 3 + s) * 1024;   // wave-uniform
            GLDS16(gp, lp);
        }
    };

    stage(0, 0);

#pragma unroll 2
    for (int ch = 0; ch < 20; ++ch) {
        __syncthreads();                  // drains chunk-ch GLDS16
        if (ch < 19) stage(ch + 1, (ch + 1) & 1);
        const char* buf = (const char*)&tile[ch & 1][0];
        bf16x8 aF[4], bF[4];
#pragma unroll
        for (int mt = 0; mt < 4; ++mt) {
            int rA = wv * 64 + mt * 16 + ln;
            int pr = rA >> 1;
            int unit = (((rA & 1) << 2) | lg) ^ (pr & 7);
            aF[mt] = *(const bf16x8*)(buf + pr * 128 + unit * 16);
        }
#pragma unroll
        for (int nt = 0; nt < 4; ++nt) {
            int rB = lh * 64 + nt * 16 + ln;
            int unit = ((bl_ << 2) | lg) ^ (rB & 7);
            bF[nt] = *(const bf16x8*)(buf + 8192 + rB * 128 + unit * 16);
        }
#pragma unroll
        for (int mt = 0; mt < 4; ++mt)
#pragma unroll
            for (int nt = 0; nt < 4; ++nt)
                acc[mt][nt] = __builtin_amdgcn_mfma_f32_16x16x32_bf16(
                    aF[mt], bF[nt], acc[mt][nt], 0, 0, 0);
    }

    // Epilogue: C/D layout col(l)=lane&15, row(v)=(lane>>4)*4+reg
    float bfin0 = bfin[0];
#pragma unroll
    for (int mt = 0; mt < 4; ++mt) {
        float bu[4];
#pragma unroll
        for (int r = 0; r < 4; ++r)
            bu[r] = bup2[v0 + wv * 64 + mt * 16 + lg * 4 + r];
        float part[4] = {0.f, 0.f, 0.f, 0.f};
#pragma unroll
        for (int nt = 0; nt < 4; ++nt) {
            float wf = Wfin[lh * 64 + nt * 16 + ln];
#pragma unroll
            for (int r = 0; r < 4; ++r)
                part[r] += wf * fmaxf(acc[mt][nt][r] + bu[r], 0.f);
        }
#pragma unroll
        for (int off = 8; off >= 1; off >>= 1)
#pragma unroll
            for (int r = 0; r < 4; ++r) part[r] += __shfl_xor(part[r], off, 64);
        if (ln == 0) {
#pragma unroll
            for (int r = 0; r < 4; ++r)
                redbuf[bl_][lh][wv * 64 + mt * 16 + lg * 4 + r] = part[r];
        }
    }
    __syncthreads();
    if (t < 256) {
        int bb = t >> 7, v = t & 127;
        float vsum = redbuf[bb][0][v] + redbuf[bb][1][v] + bfin0;
        out[(size_t)(b0 + bb) * 32000 + v0 + v] = fmaxf(vsum, 0.f);
    }
}

// ---------------------------------------------------------------------------
extern "C" void kernel_launch(void* const* d_in, const int* in_sizes, int n_in,
                              void* d_out, int out_size, void* d_ws, size_t ws_size,
                              hipStream_t stream) {
    const float* x      = (const float*)d_in[0];
    const float* W_emb  = (const float*)d_in[1];
    const float* b_emb  = (const float*)d_in[2];
    const float* W_pos1 = (const float*)d_in[3];
    const float* b_pos1 = (const float*)d_in[4];
    const float* W_red  = (const float*)d_in[5];
    const float* b_red  = (const float*)d_in[6];
    const float* W_pos2 = (const float*)d_in[7];
    const float* b_pos2 = (const float*)d_in[8];
    const float* W_red2 = (const float*)d_in[9];
    const float* b_red2 = (const float*)d_in[10];
    const float* W_pos3 = (const float*)d_in[11];
    const float* b_pos3 = (const float*)d_in[12];
    const float* W_up1  = (const float*)d_in[13];
    const float* b_up1  = (const float*)d_in[14];
    const float* W_up2  = (const float*)d_in[15];
    const float* b_up2  = (const float*)d_in[16];
    const float* W_fin  = (const float*)d_in[17];
    const float* b_fin  = (const float*)d_in[18];
    float* out = (float*)d_out;

    float* ws  = (float*)d_ws;
    float* pe1 = ws;                 // 8192
    float* pe2 = pe1 + 8192;         // 16384
    float* pe3 = pe2 + 16384;        // 40960
    float* h1  = pe3 + 40960;        // 65536
    float* s1  = h1 + 65536;         // 1024
    float* Wr1 = s1 + 1024;          // 65536
    float* h2  = Wr1 + 65536;        // 131072
    float* s2  = h2 + 131072;        // 1024
    float* Wr2 = s2 + 1024;          // 327680
    float* h3  = Wr2 + 327680;       // 327680 (layout spacer)
    unsigned short* h4b   = (unsigned short*)(h3 + 327680);          // 655360 shorts
    unsigned short* Wup2b = (unsigned short*)((float*)h4b + 327680); // 20,480,000 shorts
    float* after = (float*)Wup2b + 10240000;
    unsigned short* Whb = (unsigned short*)after;             // 2,048,000 shorts
    unsigned short* Wlb = Whb + 2048000;                      // 2,048,000 shorts
    float* partA = (float*)(Wlb + 2048000);                   // 3,276,800 floats

    prep_all<<<dim3(4384), 320, 0, stream>>>(W_emb, Whb, Wlb, W_up2, Wup2b,
                                             W_pos1, b_pos1, pe1, W_pos2, b_pos2,
                                             pe2, W_pos3, b_pos3, pe3);
    embA_mfma<<<dim3(16, SPLITS_), 256, 0, stream>>>(x, Whb, Wlb, partA);
    reduceA_kernel<<<dim3(256), 64, 0, stream>>>(partA, b_emb, pe1, h1, s1);
    wr1_kernel<<<dim3(256), 256, 0, stream>>>(W_red, s1, Wr1);
    h2_kernel<<<dim3(1024), 128, 0, stream>>>(h1, Wr1, b_red, pe2, h2, s2);
    wr2_kernel<<<dim3(320), 256, 0, stream>>>(W_red2, s2, Wr2);
    h3h4_kernel<<<dim3(256), 256, 0, stream>>>(h2, Wr2, b_red2, pe3, W_up1,
                                               b_up1, h4b);
    final_mfma_kernel<<<dim3(1024), 512, 0, stream>>>(h4b, Wup2b, b_up2, W_fin,
                                                      b_fin, out);
}

// Round 10
// 445.216 us; speedup vs baseline: 1.0567x; 1.0004x over previous
//
#include <hip/hip_runtime.h>
#include <hip/hip_bf16.h>
#include <math.h>

// Problem constants
#define B_  8
#define L_  128
#define V_  32000
#define D_  64
#define R1_ 128
#define R2_ 320
#define UP_ 640
#define SPLITS_ 50   // k-splits for stage A (640 k each)

typedef short bf16x8 __attribute__((ext_vector_type(8)));
typedef float f32x4 __attribute__((ext_vector_type(4)));

#define GLDS16(gp, lp)                                                         \
    __builtin_amdgcn_global_load_lds(                                          \
        (const __attribute__((address_space(1))) void*)(gp),                   \
        (__attribute__((address_space(3))) void*)(lp), 16, 0, 0)

static __device__ inline unsigned short f2bf(float x) {
    __hip_bfloat16 h = __float2bfloat16(x);
    return *reinterpret_cast<unsigned short*>(&h);
}

// hi/lo bf16 split: v ~= hi + lo with rel err ~2^-17
static __device__ inline void split1(float v, unsigned short& h, unsigned short& l) {
    unsigned short hb = f2bf(v);
    float hf = __uint_as_float(((unsigned int)hb) << 16);
    h = hb;
    l = f2bf(v - hf);
}

// ---------------------------------------------------------------------------
// prep_all (round-5 config: Wup2b conversion included).
__global__ __launch_bounds__(320) void prep_all(const float* __restrict__ Wemb,
                                                unsigned short* __restrict__ Whb,
                                                unsigned short* __restrict__ Wlb,
                                                const float* __restrict__ Wup2,
                                                unsigned short* __restrict__ Wup2b,
                                                const float* __restrict__ W1,
                                                const float* __restrict__ b1,
                                                float* __restrict__ o1,
                                                const float* __restrict__ W2,
                                                const float* __restrict__ b2,
                                                float* __restrict__ o2,
                                                const float* __restrict__ W3,
                                                const float* __restrict__ b3,
                                                float* __restrict__ o3) {
    __shared__ float P[640];
    int bx = blockIdx.x, t = threadIdx.x;
    if (bx < 800) {
        int u = bx * 320 + t;   // 0 .. 256000-1
        int kb = u >> 6, row = u & 63;
        const float* s = Wemb + (size_t)row * 32000 + kb * 8;
        unsigned short h8[8], l8[8];
#pragma unroll
        for (int j = 0; j < 8; ++j) split1(s[j], h8[j], l8[j]);
        *(ushort4*)&Whb[(size_t)u * 8]     = *(ushort4*)&h8[0];
        *(ushort4*)&Whb[(size_t)u * 8 + 4] = *(ushort4*)&h8[4];
        *(ushort4*)&Wlb[(size_t)u * 8]     = *(ushort4*)&l8[0];
        *(ushort4*)&Wlb[(size_t)u * 8 + 4] = *(ushort4*)&l8[4];
    } else if (bx < 1184) {
        int id = bx - 800;
        int l = id & 127;
        int stage = id >> 7;
        const float* W = (stage == 0) ? W1 : (stage == 1) ? W2 : W3;
        const float* bias = (stage == 0) ? b1 : (stage == 1) ? b2 : b3;
        float* out = (stage == 0) ? o1 : (stage == 1) ? o2 : o3;
        int outF = (stage == 0) ? 64 : (stage == 1) ? 128 : 320;
        int dEnc = 2 * outF;
        for (int m = t; m < dEnc; m += 320) {
            int i = m >> 1;
            float ang = (float)l * powf(10000.0f, -2.0f * (float)i / (float)dEnc);
            P[m] = (m & 1) ? cosf(ang) : sinf(ang);
        }
        __syncthreads();
        if (t < outF) {
            float acc = bias[t];
            const float4* w = (const float4*)(W + (size_t)t * dEnc);
            for (int m4 = 0; m4 < dEnc / 4; ++m4) {
                float4 wv = w[m4];
                float4 pv = *(const float4*)&P[m4 * 4];
                acc = fmaf(pv.x, wv.x, acc);
                acc = fmaf(pv.y, wv.y, acc);
                acc = fmaf(pv.z, wv.z, acc);
                acc = fmaf(pv.w, wv.w, acc);
            }
            out[l * outF + t] = fmaxf(acc, 0.f);
        }
    } else {
        const int n4 = (V_ * UP_) / 4;
        int stride = 3200 * 320;
        for (int i = (bx - 1184) * 320 + t; i < n4; i += stride) {
            float4 v = ((const float4*)Wup2)[i];
            ushort4 o;
            o.x = f2bf(v.x); o.y = f2bf(v.y); o.z = f2bf(v.z); o.w = f2bf(v.w);
            ((ushort4*)Wup2b)[i] = o;
        }
    }
}

// ---------------------------------------------------------------------------
// Stage A via MFMA — XCD-grouped grid: 1-D 896 blocks; decode r=bid&7 (XCD),
// rb=(bid>>3)&15, q=bid>>7, ks=r+8q (guard ks<50). All 16 sibling blocks of a
// k-split get bids congruent mod 8 -> same XCD -> the split's 164 KB Whb/Wlb
// slice is fetched into that XCD's L2 once and reused 16x (was up to 8 XCDs).
// Per-block math unchanged -> bit-identical partA.
__global__ __launch_bounds__(256) void embA_mfma(const float* __restrict__ x,
                                                 const unsigned short* __restrict__ Whb,
                                                 const unsigned short* __restrict__ Wlb,
                                                 float* __restrict__ partA) {
    __shared__ short lds[16384];   // 2 x 16 KB
    int bid = blockIdx.x;
    int r_ = bid & 7;
    int s_ = bid >> 3;              // 0..111
    int rb = s_ & 15;
    int q_ = s_ >> 4;               // 0..6
    int ks = r_ + 8 * q_;
    if (ks >= SPLITS_) return;

    int t = threadIdx.x;
    int lane = t & 63, w = t >> 6;
    int ln = lane & 15, lg = lane >> 4;
    int row0 = rb * 64;
    const float* xrow = x + (size_t)(row0 + w * 16 + ln) * 32000;

    f32x4 acc[4];
#pragma unroll
    for (int nt = 0; nt < 4; ++nt) acc[nt] = (f32x4){0.f, 0.f, 0.f, 0.f};

    float4 xc[4], xn[4];
    {
        int kb0 = (ks * 640) >> 3;
#pragma unroll
        for (int s = 0; s < 4; ++s) {
            int ubase = s * 256 + w * 64;
            const unsigned short* arr = (s < 2) ? Whb : Wlb;
            int uu = (s < 2) ? ubase : (ubase - 512);
            const char* gp = (const char*)arr + ((size_t)kb0 * 64 + uu + lane) * 16;
            char* lp = (char*)lds + ((s < 2) ? 0 : 8192) + uu * 16;
            GLDS16(gp, lp);
        }
        const float* bp = xrow + ks * 640 + lg * 8;
        xc[0] = ((const float4*)bp)[0];
        xc[1] = ((const float4*)bp)[1];
        xc[2] = ((const float4*)(bp + 32))[0];
        xc[3] = ((const float4*)(bp + 32))[1];
    }

#pragma unroll 2
    for (int ch = 0; ch < 10; ++ch) {
        __syncthreads();   // drains chunk-ch GLDS16 + x loads
        if (ch < 9) {      // kick chunk ch+1 into the other buffer
            int kb0 = (ks * 640 + (ch + 1) * 64) >> 3;
            int p = (ch + 1) & 1;
#pragma unroll
            for (int s = 0; s < 4; ++s) {
                int ubase = s * 256 + w * 64;
                const unsigned short* arr = (s < 2) ? Whb : Wlb;
                int uu = (s < 2) ? ubase : (ubase - 512);
                const char* gp = (const char*)arr + ((size_t)kb0 * 64 + uu + lane) * 16;
                char* lp = (char*)lds + p * 16384 + ((s < 2) ? 0 : 8192) + uu * 16;
                GLDS16(gp, lp);
            }
            const float* bp = xrow + ks * 640 + (ch + 1) * 64 + lg * 8;
            xn[0] = ((const float4*)bp)[0];
            xn[1] = ((const float4*)bp)[1];
            xn[2] = ((const float4*)(bp + 32))[0];
            xn[3] = ((const float4*)(bp + 32))[1];
        }
        bf16x8 ah[2], al[2];
#pragma unroll
        for (int kstep = 0; kstep < 2; ++kstep) {
            float f[8] = {xc[2 * kstep].x, xc[2 * kstep].y, xc[2 * kstep].z, xc[2 * kstep].w,
                          xc[2 * kstep + 1].x, xc[2 * kstep + 1].y, xc[2 * kstep + 1].z,
                          xc[2 * kstep + 1].w};
            unsigned short h8[8], l8[8];
#pragma unroll
            for (int j = 0; j < 8; ++j) split1(f[j], h8[j], l8[j]);
            ah[kstep] = *(bf16x8*)h8;
            al[kstep] = *(bf16x8*)l8;
        }
        const char* buf = (const char*)lds + (ch & 1) * 16384;
#pragma unroll
        for (int kstep = 0; kstep < 2; ++kstep) {
            int g = kstep * 4 + lg;
#pragma unroll
            for (int nt = 0; nt < 4; ++nt) {
                int nrow = nt * 16 + ln;
                bf16x8 bh = *(const bf16x8*)(buf + (g * 64 + nrow) * 16);
                bf16x8 bl = *(const bf16x8*)(buf + 8192 + (g * 64 + nrow) * 16);
                acc[nt] = __builtin_amdgcn_mfma_f32_16x16x32_bf16(ah[kstep], bh, acc[nt], 0, 0, 0);
                acc[nt] = __builtin_amdgcn_mfma_f32_16x16x32_bf16(ah[kstep], bl, acc[nt], 0, 0, 0);
                acc[nt] = __builtin_amdgcn_mfma_f32_16x16x32_bf16(al[kstep], bh, acc[nt], 0, 0, 0);
            }
        }
#pragma unroll
        for (int i = 0; i < 4; ++i) xc[i] = xn[i];
    }
#pragma unroll
    for (int nt = 0; nt < 4; ++nt)
#pragma unroll
        for (int r = 0; r < 4; ++r)
            partA[((size_t)ks * 1024 + row0 + w * 16 + lg * 4 + r) * 64 + nt * 16 + ln] =
                acc[nt][r];
}

// ---------------------------------------------------------------------------
// reduceA v2 (unchanged).
__global__ __launch_bounds__(64) void reduceA_kernel(const float* __restrict__ partA,
                                                     const float* __restrict__ bemb,
                                                     const float* __restrict__ pe1,
                                                     float* __restrict__ h1,
                                                     float* __restrict__ s1) {
    int lane = threadIdx.x;
    int row = blockIdx.x * 4 + (lane >> 4);
    int d0 = (lane & 15) * 4;
    float4 v = *(const float4*)&bemb[d0];
#pragma unroll 10
    for (int s = 0; s < SPLITS_; ++s) {
        float4 p = *(const float4*)&partA[((size_t)s * 1024 + row) * 64 + d0];
        v.x += p.x; v.y += p.y; v.z += p.z; v.w += p.w;
    }
    float4 pe = *(const float4*)&pe1[(row & 127) * 64 + d0];
    v.x = fmaxf(v.x, 0.f) + pe.x;
    v.y = fmaxf(v.y, 0.f) + pe.y;
    v.z = fmaxf(v.z, 0.f) + pe.z;
    v.w = fmaxf(v.w, 0.f) + pe.w;
    *(float4*)&h1[row * 64 + d0] = v;
    float sum = v.x + v.y + v.z + v.w;
#pragma unroll
    for (int off = 8; off >= 1; off >>= 1) sum += __shfl_down(sum, off);
    if ((lane & 15) == 0) s1[row] = sum;
}

// ---------------------------------------------------------------------------
// wr1 v2 (unchanged).
__global__ __launch_bounds__(256) void wr1_kernel(const float* __restrict__ Wred,
                                                  const float* __restrict__ s1,
                                                  float* __restrict__ Wr1) {
    __shared__ float ss[1024];
    __shared__ float pl[2048];
    int t = threadIdx.x, bb = blockIdx.x;
    for (int i = t; i < 1024; i += 256) ss[i] = s1[i];
    __syncthreads();
    int r = bb >> 1, jh = bb & 1;
    int jj = t & 31, ks = t >> 5;
    int j = jh * 32 + jj;
    float acc[8];
#pragma unroll
    for (int b = 0; b < 8; ++b) acc[b] = 0.f;
    const float* w = Wred + (size_t)r * 8192 + j;
#pragma unroll
    for (int kk = 0; kk < 16; ++kk) {
        int k = ks * 16 + kk;
        float wv = w[k * 64];
#pragma unroll
        for (int b = 0; b < 8; ++b) acc[b] = fmaf(ss[b * 128 + k], wv, acc[b]);
    }
#pragma unroll
    for (int b = 0; b < 8; ++b) pl[t * 8 + b] = acc[b];
    __syncthreads();
    int jj2 = t >> 3, b2 = t & 7;
    float sum = 0.f;
#pragma unroll
    for (int k2 = 0; k2 < 8; ++k2) sum += pl[(k2 * 32 + jj2) * 8 + b2];
    Wr1[((size_t)b2 * 128 + r) * 64 + jh * 32 + jj2] = sum;
}

// ---------------------------------------------------------------------------
// h2 (unchanged).
__global__ __launch_bounds__(128) void h2_kernel(const float* __restrict__ h1,
                                                 const float* __restrict__ Wr1,
                                                 const float* __restrict__ bred,
                                                 const float* __restrict__ pe2,
                                                 float* __restrict__ h2,
                                                 float* __restrict__ s2) {
    __shared__ float hrow[64];
    __shared__ float red[2];
    int row = blockIdx.x;
    int b = row >> 7, i = row & 127;
    int r = threadIdx.x;
    if (r < 64) hrow[r] = h1[row * 64 + r];
    __syncthreads();
    float acc = bred[r];
    const float4* w = (const float4*)(Wr1 + ((size_t)b * 128 + r) * 64);
#pragma unroll
    for (int j4 = 0; j4 < 16; ++j4) {
        float4 wv = w[j4];
        float4 hv = *(const float4*)&hrow[j4 * 4];
        acc = fmaf(hv.x, wv.x, acc);
        acc = fmaf(hv.y, wv.y, acc);
        acc = fmaf(hv.z, wv.z, acc);
        acc = fmaf(hv.w, wv.w, acc);
    }
    float val = fmaxf(acc, 0.f) + pe2[i * 128 + r];
    h2[row * 128 + r] = val;
    float sum = val;
    for (int off = 32; off > 0; off >>= 1) sum += __shfl_down(sum, off);
    if ((r & 63) == 0) red[r >> 6] = sum;
    __syncthreads();
    if (r == 0) s2[row] = red[0] + red[1];
}

// ---------------------------------------------------------------------------
// wr2 v2 (unchanged).
__global__ __launch_bounds__(256) void wr2_kernel(const float* __restrict__ Wred2,
                                                  const float* __restrict__ s2,
                                                  float* __restrict__ Wr2) {
    __shared__ float ss[1024];
    __shared__ float pl[2048];
    int t = threadIdx.x, r = blockIdx.x;
    for (int i = t; i < 1024; i += 256) ss[i] = s2[i];
    __syncthreads();
    int j = t & 127, ks = t >> 7;
    float acc[8];
#pragma unroll
    for (int b = 0; b < 8; ++b) acc[b] = 0.f;
    const float* w = Wred2 + (size_t)r * 16384 + j;
#pragma unroll 16
    for (int kk = 0; kk < 64; ++kk) {
        int k = ks * 64 + kk;
        float wv = w[k * 128];
#pragma unroll
        for (int b = 0; b < 8; ++b) acc[b] = fmaf(ss[b * 128 + k], wv, acc[b]);
    }
#pragma unroll
    for (int b = 0; b < 8; ++b) pl[t * 8 + b] = acc[b];
    __syncthreads();
#pragma unroll
    for (int ii = 0; ii < 4; ++ii) {
        int idx = t * 4 + ii;
        int j2 = idx >> 3, b2 = idx & 7;
        float sum = pl[j2 * 8 + b2] + pl[(128 + j2) * 8 + b2];
        Wr2[((size_t)b2 * 320 + r) * 128 + j2] = sum;
    }
}

// ---------------------------------------------------------------------------
// h3+h4 fused (unchanged).
__global__ __launch_bounds__(256) void h3h4_kernel(const float* __restrict__ h2,
                                                   const float* __restrict__ Wr2,
                                                   const float* __restrict__ bred2,
                                                   const float* __restrict__ pe3,
                                                   const float* __restrict__ Wup1,
                                                   const float* __restrict__ bup1,
                                                   unsigned short* __restrict__ h4b) {
    __shared__ float h2r[512];    // 4 rows x 128
    __shared__ float hsT[1280];   // hsT[r*4+q] = h3[row0+q][r]
    int t = threadIdx.x;
    int row0 = blockIdx.x * 4;
    int b = row0 >> 7;
    h2r[t] = h2[(size_t)row0 * 128 + t];
    h2r[t + 256] = h2[(size_t)row0 * 128 + t + 256];
    __syncthreads();
    int i_ = row0 & 127;
    for (int r = t; r < 320; r += 256) {
        const float4* w = (const float4*)(Wr2 + ((size_t)b * 320 + r) * 128);
        float a0 = bred2[r], a1 = a0, a2 = a0, a3 = a0;
#pragma unroll
        for (int j4 = 0; j4 < 32; ++j4) {
            float4 wv = w[j4];
            float4 q0 = *(const float4*)&h2r[0 * 128 + j4 * 4];
            float4 q1 = *(const float4*)&h2r[1 * 128 + j4 * 4];
            float4 q2 = *(const float4*)&h2r[2 * 128 + j4 * 4];
            float4 q3 = *(const float4*)&h2r[3 * 128 + j4 * 4];
            a0 = fmaf(q0.x, wv.x, a0); a0 = fmaf(q0.y, wv.y, a0);
            a0 = fmaf(q0.z, wv.z, a0); a0 = fmaf(q0.w, wv.w, a0);
            a1 = fmaf(q1.x, wv.x, a1); a1 = fmaf(q1.y, wv.y, a1);
            a1 = fmaf(q1.z, wv.z, a1); a1 = fmaf(q1.w, wv.w, a1);
            a2 = fmaf(q2.x, wv.x, a2); a2 = fmaf(q2.y, wv.y, a2);
            a2 = fmaf(q2.z, wv.z, a2); a2 = fmaf(q2.w, wv.w, a2);
            a3 = fmaf(q3.x, wv.x, a3); a3 = fmaf(q3.y, wv.y, a3);
            a3 = fmaf(q3.z, wv.z, a3); a3 = fmaf(q3.w, wv.w, a3);
        }
        hsT[r * 4 + 0] = fmaxf(a0, 0.f) + pe3[(i_ + 0) * 320 + r];
        hsT[r * 4 + 1] = fmaxf(a1, 0.f) + pe3[(i_ + 1) * 320 + r];
        hsT[r * 4 + 2] = fmaxf(a2, 0.f) + pe3[(i_ + 2) * 320 + r];
        hsT[r * 4 + 3] = fmaxf(a3, 0.f) + pe3[(i_ + 3) * 320 + r];
    }
    __syncthreads();
    for (int u = t; u < 640; u += 256) {
        float acc[4] = {0.f, 0.f, 0.f, 0.f};
        const float4* w = (const float4*)(Wup1 + (size_t)u * 320);
#pragma unroll 2
        for (int j4 = 0; j4 < 80; ++j4) {
            float4 wv = w[j4];
#pragma unroll
            for (int e = 0; e < 4; ++e) {
                float wc = (e == 0) ? wv.x : (e == 1) ? wv.y : (e == 2) ? wv.z : wv.w;
                float4 hv = *(const float4*)&hsT[(j4 * 4 + e) * 4];
                acc[0] = fmaf(hv.x, wc, acc[0]);
                acc[1] = fmaf(hv.y, wc, acc[1]);
                acc[2] = fmaf(hv.z, wc, acc[2]);
                acc[3] = fmaf(hv.w, wc, acc[3]);
            }
        }
        float bias = bup1[u];
#pragma unroll
        for (int q = 0; q < 4; ++q)
            h4b[(size_t)(row0 + q) * 640 + u] = f2bf(fmaxf(acc[q] + bias, 0.f));
    }
}

// ---------------------------------------------------------------------------
// final MFMA (round-9 version: XCD-grouped grid, conflict-free layout).
__global__ __launch_bounds__(512) void final_mfma_kernel(
    const unsigned short* __restrict__ h4b,
    const unsigned short* __restrict__ Wup2b,
    const float* __restrict__ bup2,
    const float* __restrict__ Wfin,
    const float* __restrict__ bfin,
    float* __restrict__ out) {
    __shared__ short tile[2][12288];       // 2 x 24 KB buffers
    __shared__ float redbuf[2][2][128];    // [b_local][l_half][v]

    // XCD-grouped decode: bid = r + 8*(j + 4*g); panel vp = g*8 + r; b0 = 2j.
    int bid = blockIdx.x;
    int r_ = bid & 7;
    int q_ = bid >> 3;
    int j_ = q_ & 3;
    int g_ = q_ >> 2;
    int vp = g_ * 8 + r_;
    if (vp >= 250) return;
    int b0 = j_ * 2;
    int v0 = vp * 128;

    int t = threadIdx.x;
    int lane = t & 63;
    int w = t >> 6;                 // 0..7
    int wv = w >> 2;                // v-half 0..1
    int wq = w & 3;                 // n-quadrant: b_local = wq>>1, l_half = wq&1
    int bl_ = wq >> 1, lh = wq & 1;
    int ln = lane & 15, lg = lane >> 4;

    f32x4 acc[4][4];
#pragma unroll
    for (int mt = 0; mt < 4; ++mt)
#pragma unroll
        for (int nt = 0; nt < 4; ++nt) acc[mt][nt] = (f32x4){0.f, 0.f, 0.f, 0.f};

    // stage chunk ch (32 k) into buffer p; LDS dest linear, source carries the
    // inverse of the read-side unit swizzle (same involution).
    auto stage = [&](int ch, int p) {
#pragma unroll
        for (int s = 0; s < 3; ++s) {
            int F = (w * 3 + s) * 1024 + lane * 16;     // byte offset in 24 KB
            const char* gp;
            if (F < 8192) {                              // A region
                int pr = F >> 7;                         // phys row 0..63
                int u = (F >> 4) & 7;                    // phys unit
                int l = u ^ (pr & 7);                    // logical
                int o = l >> 2, g = l & 3;
                gp = (const char*)Wup2b +
                     (((size_t)(v0 + 2 * pr + o)) * 640 + (size_t)(ch * 32 + g * 8)) * 2;
            } else {                                     // B region
                int FF = F - 8192;
                int pr = FF >> 7;                        // phys row 0..127
                int u = (FF >> 4) & 7;
                int l = u ^ (pr & 7);
                int region = l >> 2, g = l & 3;
                gp = (const char*)h4b +
                     (((size_t)(b0 + region) * 128 + pr) * 640 +
                      (size_t)(ch * 32 + g * 8)) * 2;
            }
            char* lp = (char*)&tile[p][0] + (w * 3 + s) * 1024;   // wave-uniform
            GLDS16(gp, lp);
        }
    };

    stage(0, 0);

#pragma unroll 2
    for (int ch = 0; ch < 20; ++ch) {
        __syncthreads();                  // drains chunk-ch GLDS16
        if (ch < 19) stage(ch + 1, (ch + 1) & 1);
        const char* buf = (const char*)&tile[ch & 1][0];
        bf16x8 aF[4], bF[4];
#pragma unroll
        for (int mt = 0; mt < 4; ++mt) {
            int rA = wv * 64 + mt * 16 + ln;
            int pr = rA >> 1;
            int unit = (((rA & 1) << 2) | lg) ^ (pr & 7);
            aF[mt] = *(const bf16x8*)(buf + pr * 128 + unit * 16);
        }
#pragma unroll
        for (int nt = 0; nt < 4; ++nt) {
            int rB = lh * 64 + nt * 16 + ln;
            int unit = ((bl_ << 2) | lg) ^ (rB & 7);
            bF[nt] = *(const bf16x8*)(buf + 8192 + rB * 128 + unit * 16);
        }
#pragma unroll
        for (int mt = 0; mt < 4; ++mt)
#pragma unroll
            for (int nt = 0; nt < 4; ++nt)
                acc[mt][nt] = __builtin_amdgcn_mfma_f32_16x16x32_bf16(
                    aF[mt], bF[nt], acc[mt][nt], 0, 0, 0);
    }

    // Epilogue: C/D layout col(l)=lane&15, row(v)=(lane>>4)*4+reg
    float bfin0 = bfin[0];
#pragma unroll
    for (int mt = 0; mt < 4; ++mt) {
        float bu[4];
#pragma unroll
        for (int r = 0; r < 4; ++r)
            bu[r] = bup2[v0 + wv * 64 + mt * 16 + lg * 4 + r];
        float part[4] = {0.f, 0.f, 0.f, 0.f};
#pragma unroll
        for (int nt = 0; nt < 4; ++nt) {
            float wf = Wfin[lh * 64 + nt * 16 + ln];
#pragma unroll
            for (int r = 0; r < 4; ++r)
                part[r] += wf * fmaxf(acc[mt][nt][r] + bu[r], 0.f);
        }
#pragma unroll
        for (int off = 8; off >= 1; off >>= 1)
#pragma unroll
            for (int r = 0; r < 4; ++r) part[r] += __shfl_xor(part[r], off, 64);
        if (ln == 0) {
#pragma unroll
            for (int r = 0; r < 4; ++r)
                redbuf[bl_][lh][wv * 64 + mt * 16 + lg * 4 + r] = part[r];
        }
    }
    __syncthreads();
    if (t < 256) {
        int bb = t >> 7, v = t & 127;
        float vsum = redbuf[bb][0][v] + redbuf[bb][1][v] + bfin0;
        out[(size_t)(b0 + bb) * 32000 + v0 + v] = fmaxf(vsum, 0.f);
    }
}

// ---------------------------------------------------------------------------
extern "C" void kernel_launch(void* const* d_in, const int* in_sizes, int n_in,
                              void* d_out, int out_size, void* d_ws, size_t ws_size,
                              hipStream_t stream) {
    const float* x      = (const float*)d_in[0];
    const float* W_emb  = (const float*)d_in[1];
    const float* b_emb  = (const float*)d_in[2];
    const float* W_pos1 = (const float*)d_in[3];
    const float* b_pos1 = (const float*)d_in[4];
    const float* W_red  = (const float*)d_in[5];
    const float* b_red  = (const float*)d_in[6];
    const float* W_pos2 = (const float*)d_in[7];
    const float* b_pos2 = (const float*)d_in[8];
    const float* W_red2 = (const float*)d_in[9];
    const float* b_red2 = (const float*)d_in[10];
    const float* W_pos3 = (const float*)d_in[11];
    const float* b_pos3 = (const float*)d_in[12];
    const float* W_up1  = (const float*)d_in[13];
    const float* b_up1  = (const float*)d_in[14];
    const float* W_up2  = (const float*)d_in[15];
    const float* b_up2  = (const float*)d_in[16];
    const float* W_fin  = (const float*)d_in[17];
    const float* b_fin  = (const float*)d_in[18];
    float* out = (float*)d_out;

    float* ws  = (float*)d_ws;
    float* pe1 = ws;                 // 8192
    float* pe2 = pe1 + 8192;         // 16384
    float* pe3 = pe2 + 16384;        // 40960
    float* h1  = pe3 + 40960;        // 65536
    float* s1  = h1 + 65536;         // 1024
    float* Wr1 = s1 + 1024;          // 65536
    float* h2  = Wr1 + 65536;        // 131072
    float* s2  = h2 + 131072;        // 1024
    float* Wr2 = s2 + 1024;          // 327680
    float* h3  = Wr2 + 327680;       // 327680 (layout spacer)
    unsigned short* h4b   = (unsigned short*)(h3 + 327680);          // 655360 shorts
    unsigned short* Wup2b = (unsigned short*)((float*)h4b + 327680); // 20,480,000 shorts
    float* after = (float*)Wup2b + 10240000;
    unsigned short* Whb = (unsigned short*)after;             // 2,048,000 shorts
    unsigned short* Wlb = Whb + 2048000;                      // 2,048,000 shorts
    float* partA = (float*)(Wlb + 2048000);                   // 3,276,800 floats

    prep_all<<<dim3(4384), 320, 0, stream>>>(W_emb, Whb, Wlb, W_up2, Wup2b,
                                             W_pos1, b_pos1, pe1, W_pos2, b_pos2,
                                             pe2, W_pos3, b_pos3, pe3);
    embA_mfma<<<dim3(896), 256, 0, stream>>>(x, Whb, Wlb, partA);
    reduceA_kernel<<<dim3(256), 64, 0, stream>>>(partA, b_emb, pe1, h1, s1);
    wr1_kernel<<<dim3(256), 256, 0, stream>>>(W_red, s1, Wr1);
    h2_kernel<<<dim3(1024), 128, 0, stream>>>(h1, Wr1, b_red, pe2, h2, s2);
    wr2_kernel<<<dim3(320), 256, 0, stream>>>(W_red2, s2, Wr2);
    h3h4_kernel<<<dim3(256), 256, 0, stream>>>(h2, Wr2, b_red2, pe3, W_up1,
                                               b_up1, h4b);
    final_mfma_kernel<<<dim3(1024), 512, 0, stream>>>(h4b, Wup2b, b_up2, W_fin,
                                                      b_fin, out);
}